// Round 4
// baseline (2063.599 us; speedup 1.0000x reference)
//
#include <hip/hip_runtime.h>

#define Bsz 256
#define Tsz 512
#define Isz 64
#define Hsz 128
#define G4  512   // 4*H

typedef _Float16 f16;
typedef _Float16 f16x8 __attribute__((ext_vector_type(8)));
typedef _Float16 f16x4 __attribute__((ext_vector_type(4)));
typedef float floatx4 __attribute__((ext_vector_type(4)));

#define MFMA(A, B, C) __builtin_amdgcn_mfma_f32_16x16x32_f16((A), (B), (C), 0, 0, 0)

__device__ __forceinline__ float sigm_f(float x) {
  float e = __builtin_amdgcn_exp2f(x * -1.4426950408889634f);
  return __builtin_amdgcn_rcpf(1.0f + e);
}
__device__ __forceinline__ float tanh_f(float x) {
  float e = __builtin_amdgcn_exp2f(x * -2.8853900817779268f);
  return 2.0f * __builtin_amdgcn_rcpf(1.0f + e) - 1.0f;
}

// fp32 -> fp16 convert, 4 elems/thread
__global__ void cvt_f32_f16(const float* __restrict__ in, f16* __restrict__ out, int n4) {
  int i = blockIdx.x * blockDim.x + threadIdx.x;
  if (i < n4) {
    float4 v = ((const float4*)in)[i];
    f16x4 o;
    o[0] = (f16)v.x; o[1] = (f16)v.y; o[2] = (f16)v.z; o[3] = (f16)v.w;
    ((f16x4*)out)[i] = o;
  }
}

// load one MFMA B-fragment (8 contiguous k) from fp32 weight row, converting to f16
__device__ __forceinline__ f16x8 load_wfrag(const float* __restrict__ W, int n, int stride, int k) {
  const float* p = W + (size_t)n * stride + k;
  float4 a = *(const float4*)p;
  float4 b = *(const float4*)(p + 4);
  f16x8 r;
  r[0] = (f16)a.x; r[1] = (f16)a.y; r[2] = (f16)a.z; r[3] = (f16)a.w;
  r[4] = (f16)b.x; r[5] = (f16)b.y; r[6] = (f16)b.z; r[7] = (f16)b.w;
  return r;
}

// Shared-denominator LSTM cell: 5 exp2 + 2 rcp (vs 10 trans naive).
// c' = [c*(1+ei)(1+eg) + (1+ef)(1-eg)] / [(1+ef)(1+ei)(1+eg)]
// h  = (1-ec) / [(1+eo)(1+ec)]
// exp2 args clamped at +30 (sigma==0/1 regime, exact), preventing inf*0.
__device__ __forceinline__ float lstm_cell(float ipre, float fpre, float gpre,
                                           float opre, float& c) {
  const float ei = __builtin_amdgcn_exp2f(fminf(ipre * -1.4426950408889634f, 30.f));
  const float ef = __builtin_amdgcn_exp2f(fminf(fpre * -1.4426950408889634f, 30.f));
  const float eg = __builtin_amdgcn_exp2f(fminf(gpre * -2.8853900817779268f, 30.f));
  const float eo = __builtin_amdgcn_exp2f(fminf(opre * -1.4426950408889634f, 30.f));
  const float pf1 = 1.f + ef;
  const float P = (1.f + ei) * (1.f + eg);
  const float num = fmaf(c, P, pf1 * (1.f - eg));
  const float cn = num * __builtin_amdgcn_rcpf(pf1 * P);
  c = cn;
  const float ec = __builtin_amdgcn_exp2f(fminf(cn * -2.8853900817779268f, 30.f));
  return (1.f - ec) * __builtin_amdgcn_rcpf((1.f + eo) * (1.f + ec));
}

// Layer-0 BiLSTM scan, input projection fused but OFF the recurrent path:
// xacc(t+1) is computed after the cell update (pre-barrier), carried across
// the barrier as the accumulator init. Post-barrier chain: ds_read h ->
// 4-deep rec MFMA -> 7-trans cell -> write h. One barrier/step.
// 512 thr / 8 waves; wave w owns j-slice [16w,16w+16) of ALL 4 gates.
// blocks 0..15 forward, 16..31 reverse. Writes hs[b][t][dir*128+j] (f16).
__global__ __launch_bounds__(512, 1) void lstm_scan_l0(
    const f16* __restrict__ xf,
    const float* __restrict__ Wih_f, const float* __restrict__ Whh_f,
    const float* __restrict__ bih_f, const float* __restrict__ bhh_f,
    const float* __restrict__ Wih_r, const float* __restrict__ Whh_r,
    const float* __restrict__ bih_r, const float* __restrict__ bhh_r,
    f16* __restrict__ hs) {
  const int dir = ((int)blockIdx.x >= 16) ? 1 : 0;
  const int bb = ((int)blockIdx.x & 15) * 16;
  const float* __restrict__ Wih = dir ? Wih_r : Wih_f;
  const float* __restrict__ Whh = dir ? Whh_r : Whh_f;
  const float* __restrict__ bih = dir ? bih_r : bih_f;
  const float* __restrict__ bhh = dir ? bhh_r : bhh_f;

  __shared__ __align__(16) f16 hq[2][16][136];   // h state, double-buffered

  const int tid = threadIdx.x;
  const int lane = tid & 63;
  const int w = tid >> 6;
  const int l15 = lane & 15;
  const int q = lane >> 4;
  const int jcol = w * 16 + l15;

  // W fragments: gate g cols n = g*128 + jcol; B[k][n]=W[n][k], k = kt*32+q*8+jj
  f16x8 wi[4][2], wh[4][4];
  float bsum[4];
#pragma unroll
  for (int g = 0; g < 4; ++g) {
    const int n = g * 128 + jcol;
#pragma unroll
    for (int kt = 0; kt < 2; ++kt) wi[g][kt] = load_wfrag(Wih, n, Isz, kt * 32 + q * 8);
#pragma unroll
    for (int kt = 0; kt < 4; ++kt) wh[g][kt] = load_wfrag(Whh, n, Hsz, kt * 32 + q * 8);
    bsum[g] = bih[n] + bhh[n];
  }

  for (int i = tid; i < 16 * 136; i += 512) (&hq[0][0][0])[i] = (f16)0.f;

  float cst[4] = {0.f, 0.f, 0.f, 0.f};  // c[m=4q+r][jcol]

  const int t0 = dir ? (Tsz - 1) : 0;
  const int dt = dir ? -1 : 1;

  // x A-frags: row bb+l15, k = q*8 + 32*kt
  const f16* xp = xf + ((size_t)(bb + l15) * Tsz + t0) * Isz + q * 8;
  const ptrdiff_t xstep = (ptrdiff_t)dt * Isz;

  // prime: xacc = bias + xproj(t0); xp then points at t0+dt
  floatx4 xacc[4];
  {
    f16x8 x0 = *(const f16x8*)xp;
    f16x8 x1 = *(const f16x8*)(xp + 32);
    xp += xstep;
#pragma unroll
    for (int g = 0; g < 4; ++g) {
      xacc[g][0] = bsum[g]; xacc[g][1] = bsum[g];
      xacc[g][2] = bsum[g]; xacc[g][3] = bsum[g];
      xacc[g] = MFMA(x0, wi[g][0], xacc[g]);
      xacc[g] = MFMA(x1, wi[g][1], xacc[g]);
    }
  }

  // hs store base for this lane: rows m=4q+r, col dir*128+jcol
  f16* hsp = hs + ((size_t)(bb + 4 * q) * Tsz + t0) * 256 + dir * 128 + jcol;
  const ptrdiff_t hstep = (ptrdiff_t)dt * 256;

  __syncthreads();

  for (int t = 0; t < Tsz; ++t) {
    const bool more = (t + 1 < Tsz);
    // issue x(t+1) loads now; consumed at bottom of this iteration
    f16x8 xn0, xn1;
    if (more) {
      xn0 = *(const f16x8*)xp;
      xn1 = *(const f16x8*)(xp + 32);
      xp += xstep;
    }

    // recurrent part: 4-deep dependent chain into xacc (= bias + x-proj)
    f16x8 ah[4];
#pragma unroll
    for (int kt = 0; kt < 4; ++kt)
      ah[kt] = *(const f16x8*)(&hq[t & 1][l15][kt * 32 + q * 8]);
#pragma unroll
    for (int kt = 0; kt < 4; ++kt)
#pragma unroll
      for (int g = 0; g < 4; ++g) xacc[g] = MFMA(ah[kt], wh[g][kt], xacc[g]);

    // in-register cell update; write h to other hq buffer + global hs
#pragma unroll
    for (int r = 0; r < 4; ++r) {
      const float h = lstm_cell(xacc[0][r], xacc[1][r], xacc[2][r], xacc[3][r], cst[r]);
      const f16 hf = (f16)h;
      hq[(t + 1) & 1][4 * q + r][jcol] = hf;
      hsp[(size_t)r * Tsz * 256] = hf;
    }
    hsp += hstep;

    // prepare next step's gate init off the critical path
    if (more) {
#pragma unroll
      for (int g = 0; g < 4; ++g) {
        xacc[g][0] = bsum[g]; xacc[g][1] = bsum[g];
        xacc[g][2] = bsum[g]; xacc[g][3] = bsum[g];
        xacc[g] = MFMA(xn0, wi[g][0], xacc[g]);
        xacc[g] = MFMA(xn1, wi[g][1], xacc[g]);
      }
    }
    __syncthreads();
  }
}

// Layer-1 forward scan, input projection (K=256 over hs) fused, same
// off-critical-path structure. 16 blocks. x-frags read per-lane from global
// hs (cross-wave duplication L1-served).
__global__ __launch_bounds__(512, 1) void lstm_scan_l1(
    const f16* __restrict__ hs,
    const float* __restrict__ Wih, const float* __restrict__ Whh,
    const float* __restrict__ bih, const float* __restrict__ bhh,
    float* __restrict__ hfinal) {
  const int bb = (int)blockIdx.x * 16;

  __shared__ __align__(16) f16 hq[2][16][136];

  const int tid = threadIdx.x;
  const int lane = tid & 63;
  const int w = tid >> 6;
  const int l15 = lane & 15;
  const int q = lane >> 4;
  const int jcol = w * 16 + l15;

  f16x8 wi[4][8], wh[4][4];
  float bsum[4];
#pragma unroll
  for (int g = 0; g < 4; ++g) {
    const int n = g * 128 + jcol;
#pragma unroll
    for (int kt = 0; kt < 8; ++kt) wi[g][kt] = load_wfrag(Wih, n, 256, kt * 32 + q * 8);
#pragma unroll
    for (int kt = 0; kt < 4; ++kt) wh[g][kt] = load_wfrag(Whh, n, Hsz, kt * 32 + q * 8);
    bsum[g] = bih[n] + bhh[n];
  }

  for (int i = tid; i < 16 * 136; i += 512) (&hq[0][0][0])[i] = (f16)0.f;

  float cst[4] = {0.f, 0.f, 0.f, 0.f};

  // x source: hs row bb+l15, k = kt*32 + q*8, time index in the middle
  const f16* sp = hs + (size_t)(bb + l15) * Tsz * 256 + q * 8;

  floatx4 xacc[4];
  {
#pragma unroll
    for (int g = 0; g < 4; ++g) {
      xacc[g][0] = bsum[g]; xacc[g][1] = bsum[g];
      xacc[g][2] = bsum[g]; xacc[g][3] = bsum[g];
    }
#pragma unroll
    for (int kt = 0; kt < 8; ++kt) {
      f16x8 xa = *(const f16x8*)(sp + kt * 32);
#pragma unroll
      for (int g = 0; g < 4; ++g) xacc[g] = MFMA(xa, wi[g][kt], xacc[g]);
    }
  }
  __syncthreads();

  for (int t = 0; t < Tsz; ++t) {
    const bool more = (t + 1 < Tsz);
    f16x8 xn[8];
    if (more) {
      const f16* xq = sp + (size_t)(t + 1) * 256;
#pragma unroll
      for (int kt = 0; kt < 8; ++kt) xn[kt] = *(const f16x8*)(xq + kt * 32);
    }

    f16x8 ah[4];
#pragma unroll
    for (int kt = 0; kt < 4; ++kt)
      ah[kt] = *(const f16x8*)(&hq[t & 1][l15][kt * 32 + q * 8]);
#pragma unroll
    for (int kt = 0; kt < 4; ++kt)
#pragma unroll
      for (int g = 0; g < 4; ++g) xacc[g] = MFMA(ah[kt], wh[g][kt], xacc[g]);

#pragma unroll
    for (int r = 0; r < 4; ++r) {
      const float h = lstm_cell(xacc[0][r], xacc[1][r], xacc[2][r], xacc[3][r], cst[r]);
      hq[(t + 1) & 1][4 * q + r][jcol] = (f16)h;
      if (t == Tsz - 1) hfinal[(size_t)(bb + 4 * q + r) * Hsz + jcol] = h;
    }

    if (more) {
#pragma unroll
      for (int g = 0; g < 4; ++g) {
        xacc[g][0] = bsum[g]; xacc[g][1] = bsum[g];
        xacc[g][2] = bsum[g]; xacc[g][3] = bsum[g];
      }
#pragma unroll
      for (int kt = 0; kt < 8; ++kt)
#pragma unroll
        for (int g = 0; g < 4; ++g) xacc[g] = MFMA(xn[kt], wi[g][kt], xacc[g]);
    }
    __syncthreads();
  }
}

// L1-reverse single step (h0=c0=0 -> Whh term vanishes) + FC head. 1 block/batch.
__global__ __launch_bounds__(512) void tail_kernel(
    const f16* __restrict__ hs, const float* __restrict__ hfinal,
    const float* __restrict__ Wr, const float* __restrict__ br1,
    const float* __restrict__ br2, const float* __restrict__ fc1w,
    const float* __restrict__ fc1b, const float* __restrict__ fc2w,
    const float* __restrict__ fc2b, float* __restrict__ out) {
  const int b = blockIdx.x;
  const int tid = threadIdx.x;
  __shared__ float hrow[256];
  __shared__ float gact[512];
  __shared__ float last[256];
  __shared__ float hid[128];
  __shared__ float psum[128];

  const size_t row = ((size_t)b * Tsz + (Tsz - 1)) * 256;
  if (tid < 256) hrow[tid] = (float)hs[row + tid];
  __syncthreads();

  {
    float a = br1[tid] + br2[tid];
    const float* wr = Wr + (size_t)tid * 256;
#pragma unroll 8
    for (int k = 0; k < 256; ++k) a += hrow[k] * wr[k];
    gact[tid] = (tid >= 256 && tid < 384) ? tanh_f(a) : sigm_f(a);
  }
  __syncthreads();

  if (tid < 128) {
    const float c = gact[tid] * gact[256 + tid];      // sig(i)*tanh(g), c0=0
    const float hb = gact[384 + tid] * tanh_f(c);
    last[tid] = hfinal[(size_t)b * Hsz + tid];
    last[128 + tid] = hb;
  }
  __syncthreads();

  if (tid < 128) {
    float a = fc1b[tid];
    const float* w1 = fc1w + (size_t)tid * 256;
#pragma unroll 8
    for (int k = 0; k < 256; ++k) a += last[k] * w1[k];
    hid[tid] = fmaxf(a, 0.f);
  }
  __syncthreads();
  if (tid < 128) psum[tid] = hid[tid] * fc2w[tid];
  __syncthreads();
  if (tid == 0) {
    float s = fc2b[0];
    for (int k = 0; k < 128; ++k) s += psum[k];
    out[b] = s;
  }
}

extern "C" void kernel_launch(void* const* d_in, const int* in_sizes, int n_in,
                              void* d_out, int out_size, void* d_ws, size_t ws_size,
                              hipStream_t stream) {
  (void)in_sizes; (void)n_in; (void)out_size;
  const float* x = (const float*)d_in[0];
  const float* Wih_l0 = (const float*)d_in[1];
  const float* Whh_l0 = (const float*)d_in[2];
  const float* bih_l0 = (const float*)d_in[3];
  const float* bhh_l0 = (const float*)d_in[4];
  const float* Wih_l0r = (const float*)d_in[5];
  const float* Whh_l0r = (const float*)d_in[6];
  const float* bih_l0r = (const float*)d_in[7];
  const float* bhh_l0r = (const float*)d_in[8];
  const float* Wih_l1 = (const float*)d_in[9];
  const float* Whh_l1 = (const float*)d_in[10];
  const float* bih_l1 = (const float*)d_in[11];
  const float* bhh_l1 = (const float*)d_in[12];
  const float* Wih_l1r = (const float*)d_in[13];
  // d_in[14] = W_hh_l1r unused (reverse h0 = 0)
  const float* bih_l1r = (const float*)d_in[15];
  const float* bhh_l1r = (const float*)d_in[16];
  const float* fc1w = (const float*)d_in[17];
  const float* fc1b = (const float*)d_in[18];
  const float* fc2w = (const float*)d_in[19];
  const float* fc2b = (const float*)d_in[20];
  float* out = (float*)d_out;

  char* ws = (char*)d_ws;
  const size_t M = (size_t)Bsz * Tsz;        // 131072
  const size_t XFB = M * Isz * 2;            // 16.8 MB  x in f16
  const size_t HSB = M * 256 * 2;            // 67.1 MB  hs in f16
  const size_t HFB = (size_t)Bsz * Hsz * 4;  // 131 KB   L1 fwd final h
  const size_t need = XFB + HSB + HFB;
  if (ws_size < need) return;  // fail clean (absmax), not fault

  size_t off = 0;
  f16* xf = (f16*)(ws + off); off += XFB;
  f16* hsb = (f16*)(ws + off); off += HSB;
  float* hfinal = (float*)(ws + off); off += HFB;

  const int n4 = (int)(M * Isz / 4);
  cvt_f32_f16<<<dim3((n4 + 255) / 256), dim3(256), 0, stream>>>(x, xf, n4);

  lstm_scan_l0<<<dim3(32), dim3(512), 0, stream>>>(
      xf, Wih_l0, Whh_l0, bih_l0, bhh_l0, Wih_l0r, Whh_l0r, bih_l0r, bhh_l0r, hsb);

  lstm_scan_l1<<<dim3(16), dim3(512), 0, stream>>>(
      hsb, Wih_l1, Whh_l1, bih_l1, bhh_l1, hfinal);

  tail_kernel<<<dim3(256), dim3(512), 0, stream>>>(
      hsb, hfinal, Wih_l1r, bih_l1r, bhh_l1r, fc1w, fc1b, fc2w, fc2b, out);
}

// Round 5
// 1591.023 us; speedup vs baseline: 1.2970x; 1.2970x over previous
//
#include <hip/hip_runtime.h>

#define Bsz 256
#define Tsz 512
#define Isz 64
#define Hsz 128
#define G4  512   // 4*H

typedef _Float16 f16;
typedef _Float16 f16x8 __attribute__((ext_vector_type(8)));
typedef _Float16 f16x4 __attribute__((ext_vector_type(4)));
typedef float floatx4 __attribute__((ext_vector_type(4)));

#define MFMA(A, B, C) __builtin_amdgcn_mfma_f32_16x16x32_f16((A), (B), (C), 0, 0, 0)

// LDS-only barrier: drains lgkmcnt (LDS) but NOT vmcnt -> global loads/stores
// issued inside the recurrent loop do not serialize each step. Correct because
// no in-loop global write is read by any other wave during the loop.
__device__ __forceinline__ void lds_barrier() {
  asm volatile("s_waitcnt lgkmcnt(0)\n\ts_barrier" ::: "memory");
}

__device__ __forceinline__ float sigm_f(float x) {
  float e = __builtin_amdgcn_exp2f(x * -1.4426950408889634f);
  return __builtin_amdgcn_rcpf(1.0f + e);
}
__device__ __forceinline__ float tanh_f(float x) {
  float e = __builtin_amdgcn_exp2f(x * -2.8853900817779268f);
  return 2.0f * __builtin_amdgcn_rcpf(1.0f + e) - 1.0f;
}

// fp32 -> fp16 convert, 4 elems/thread
__global__ void cvt_f32_f16(const float* __restrict__ in, f16* __restrict__ out, int n4) {
  int i = blockIdx.x * blockDim.x + threadIdx.x;
  if (i < n4) {
    float4 v = ((const float4*)in)[i];
    f16x4 o;
    o[0] = (f16)v.x; o[1] = (f16)v.y; o[2] = (f16)v.z; o[3] = (f16)v.w;
    ((f16x4*)out)[i] = o;
  }
}

// load one MFMA B-fragment (8 contiguous k) from fp32 weight row, converting to f16
__device__ __forceinline__ f16x8 load_wfrag(const float* __restrict__ W, int n, int stride, int k) {
  const float* p = W + (size_t)n * stride + k;
  float4 a = *(const float4*)p;
  float4 b = *(const float4*)(p + 4);
  f16x8 r;
  r[0] = (f16)a.x; r[1] = (f16)a.y; r[2] = (f16)a.z; r[3] = (f16)a.w;
  r[4] = (f16)b.x; r[5] = (f16)b.y; r[6] = (f16)b.z; r[7] = (f16)b.w;
  return r;
}

// Shared-denominator LSTM cell: 5 exp2 + 2 rcp (vs 10 trans naive).
__device__ __forceinline__ float lstm_cell(float ipre, float fpre, float gpre,
                                           float opre, float& c) {
  const float ei = __builtin_amdgcn_exp2f(fminf(ipre * -1.4426950408889634f, 30.f));
  const float ef = __builtin_amdgcn_exp2f(fminf(fpre * -1.4426950408889634f, 30.f));
  const float eg = __builtin_amdgcn_exp2f(fminf(gpre * -2.8853900817779268f, 30.f));
  const float eo = __builtin_amdgcn_exp2f(fminf(opre * -1.4426950408889634f, 30.f));
  const float pf1 = 1.f + ef;
  const float P = (1.f + ei) * (1.f + eg);
  const float num = fmaf(c, P, pf1 * (1.f - eg));
  const float cn = num * __builtin_amdgcn_rcpf(pf1 * P);
  c = cn;
  const float ec = __builtin_amdgcn_exp2f(fminf(cn * -2.8853900817779268f, 30.f));
  return (1.f - ec) * __builtin_amdgcn_rcpf((1.f + eo) * (1.f + ec));
}

// Layer-0 BiLSTM scan. 512 thr / 8 waves; wave w owns j-slice [16w,16w+16) of
// all 4 gates -> in-register cell update. x staged global->LDS 2 steps ahead
// (no 8x cross-wave duplication); x-projection MFMAs run off the recurrent
// path into nacc, carried to the next step as gacc. One LDS-only barrier/step.
// blocks 0..15 forward, 16..31 reverse. Writes hs[b][t][dir*128+j] (f16).
__global__ __launch_bounds__(512, 1) void lstm_scan_l0(
    const f16* __restrict__ xf,
    const float* __restrict__ Wih_f, const float* __restrict__ Whh_f,
    const float* __restrict__ bih_f, const float* __restrict__ bhh_f,
    const float* __restrict__ Wih_r, const float* __restrict__ Whh_r,
    const float* __restrict__ bih_r, const float* __restrict__ bhh_r,
    f16* __restrict__ hs) {
  const int dir = ((int)blockIdx.x >= 16) ? 1 : 0;
  const int bb = ((int)blockIdx.x & 15) * 16;
  const float* __restrict__ Wih = dir ? Wih_r : Wih_f;
  const float* __restrict__ Whh = dir ? Whh_r : Whh_f;
  const float* __restrict__ bih = dir ? bih_r : bih_f;
  const float* __restrict__ bhh = dir ? bhh_r : bhh_f;

  __shared__ __align__(16) f16 hq[2][16][136];   // h state, double-buffered
  __shared__ __align__(16) f16 xq[2][16][72];    // staged x rows (64 + pad)

  const int tid = threadIdx.x;
  const int lane = tid & 63;
  const int w = tid >> 6;
  const int l15 = lane & 15;
  const int q = lane >> 4;
  const int jcol = w * 16 + l15;

  f16x8 wi[4][2], wh[4][4];
  float bsum[4];
#pragma unroll
  for (int g = 0; g < 4; ++g) {
    const int n = g * 128 + jcol;
#pragma unroll
    for (int kt = 0; kt < 2; ++kt) wi[g][kt] = load_wfrag(Wih, n, Isz, kt * 32 + q * 8);
#pragma unroll
    for (int kt = 0; kt < 4; ++kt) wh[g][kt] = load_wfrag(Whh, n, Hsz, kt * 32 + q * 8);
    bsum[g] = bih[n] + bhh[n];
  }

  for (int i = tid; i < 16 * 136; i += 512) (&hq[0][0][0])[i] = (f16)0.f;

  float cst[4] = {0.f, 0.f, 0.f, 0.f};
  const int t0 = dir ? (Tsz - 1) : 0;
  const int dt = dir ? -1 : 1;
  const ptrdiff_t xstep = (ptrdiff_t)dt * Isz;

  // prime gacc = bias + xproj(x(t0)) straight from global (one-time)
  floatx4 gacc[4];
  {
    const f16* pp = xf + ((size_t)(bb + l15) * Tsz + t0) * Isz + q * 8;
    f16x8 x0 = *(const f16x8*)pp;
    f16x8 x1 = *(const f16x8*)(pp + 32);
#pragma unroll
    for (int g = 0; g < 4; ++g) {
      gacc[g][0] = bsum[g]; gacc[g][1] = bsum[g];
      gacc[g][2] = bsum[g]; gacc[g][3] = bsum[g];
      gacc[g] = MFMA(x0, wi[g][0], gacc[g]);
      gacc[g] = MFMA(x1, wi[g][1], gacc[g]);
    }
  }

  // staging: tid<128, row sm, 8-f16 chunk sc. prime xq[1]=x(t0+dt), ld=x(t0+2dt)
  const int sm = (tid >> 3) & 15;
  const int sc = tid & 7;
  const f16* spg = xf + ((size_t)(bb + sm) * Tsz + t0) * Isz + sc * 8;
  const f16* spn = spg + 3 * xstep;
  f16x8 ld;
  if (tid < 128) {
    *(f16x8*)(&xq[1][sm][sc * 8]) = *(const f16x8*)(spg + xstep);
    ld = *(const f16x8*)(spg + 2 * xstep);
  }

  // hs store base: rows m=4q+r, col dir*128+jcol
  f16* hsp = hs + ((size_t)(bb + 4 * q) * Tsz + t0) * 256 + dir * 128 + jcol;
  const ptrdiff_t hstep = (ptrdiff_t)dt * 256;

  __syncthreads();

  for (int t = 0; t < Tsz; ++t) {
    // x-frags for step t+1 (published at t-1)
    f16x8 xa0, xa1;
    if (t + 1 < Tsz) {
      const f16* xrow = &xq[(t + 1) & 1][l15][0];
      xa0 = *(const f16x8*)(xrow + q * 8);
      xa1 = *(const f16x8*)(xrow + 32 + q * 8);
    }

    // recurrent 4-deep chain into gacc (= bias + xproj(t))
    f16x8 ah[4];
#pragma unroll
    for (int kt = 0; kt < 4; ++kt)
      ah[kt] = *(const f16x8*)(&hq[t & 1][l15][kt * 32 + q * 8]);
#pragma unroll
    for (int kt = 0; kt < 4; ++kt)
#pragma unroll
      for (int g = 0; g < 4; ++g) gacc[g] = MFMA(ah[kt], wh[g][kt], gacc[g]);

    // cell update; h -> hq other buffer + global hs (fire-and-forget)
#pragma unroll
    for (int r = 0; r < 4; ++r) {
      const float h = lstm_cell(gacc[0][r], gacc[1][r], gacc[2][r], gacc[3][r], cst[r]);
      const f16 hf = (f16)h;
      hq[(t + 1) & 1][4 * q + r][jcol] = hf;
      hsp[(size_t)r * Tsz * 256] = hf;
    }
    hsp += hstep;

    // staging pipeline: publish x(t+2), load x(t+3)
    if (tid < 128) {
      if (t + 2 < Tsz) *(f16x8*)(&xq[t & 1][sm][sc * 8]) = ld;
      if (t + 3 < Tsz) { ld = *(const f16x8*)spn; spn += xstep; }
    }

    // x-projection for t+1 (independent 2-deep chains, off recurrent path)
    if (t + 1 < Tsz) {
      floatx4 nacc[4];
#pragma unroll
      for (int g = 0; g < 4; ++g) {
        nacc[g][0] = bsum[g]; nacc[g][1] = bsum[g];
        nacc[g][2] = bsum[g]; nacc[g][3] = bsum[g];
        nacc[g] = MFMA(xa0, wi[g][0], nacc[g]);
        nacc[g] = MFMA(xa1, wi[g][1], nacc[g]);
        gacc[g] = nacc[g];
      }
    }
    lds_barrier();
  }
}

// Layer-1 forward scan, input projection (K=256 over hs) fused, same staged
// off-critical-path structure. 16 blocks.
__global__ __launch_bounds__(512, 1) void lstm_scan_l1(
    const f16* __restrict__ hs,
    const float* __restrict__ Wih, const float* __restrict__ Whh,
    const float* __restrict__ bih, const float* __restrict__ bhh,
    float* __restrict__ hfinal) {
  const int bb = (int)blockIdx.x * 16;

  __shared__ __align__(16) f16 hq[2][16][136];
  __shared__ __align__(16) f16 xq[2][16][264];   // staged hs rows (256 + pad)

  const int tid = threadIdx.x;
  const int lane = tid & 63;
  const int w = tid >> 6;
  const int l15 = lane & 15;
  const int q = lane >> 4;
  const int jcol = w * 16 + l15;

  f16x8 wi[4][8], wh[4][4];
  float bsum[4];
#pragma unroll
  for (int g = 0; g < 4; ++g) {
    const int n = g * 128 + jcol;
#pragma unroll
    for (int kt = 0; kt < 8; ++kt) wi[g][kt] = load_wfrag(Wih, n, 256, kt * 32 + q * 8);
#pragma unroll
    for (int kt = 0; kt < 4; ++kt) wh[g][kt] = load_wfrag(Whh, n, Hsz, kt * 32 + q * 8);
    bsum[g] = bih[n] + bhh[n];
  }

  for (int i = tid; i < 16 * 136; i += 512) (&hq[0][0][0])[i] = (f16)0.f;

  float cst[4] = {0.f, 0.f, 0.f, 0.f};

  // prime gacc = bias + xproj(hs(t=0)) straight from global (one-time)
  floatx4 gacc[4];
  {
    const f16* pp = hs + (size_t)(bb + l15) * Tsz * 256 + q * 8;
#pragma unroll
    for (int g = 0; g < 4; ++g) {
      gacc[g][0] = bsum[g]; gacc[g][1] = bsum[g];
      gacc[g][2] = bsum[g]; gacc[g][3] = bsum[g];
    }
#pragma unroll
    for (int kt = 0; kt < 8; ++kt) {
      f16x8 xa = *(const f16x8*)(pp + kt * 32);
#pragma unroll
      for (int g = 0; g < 4; ++g) gacc[g] = MFMA(xa, wi[g][kt], gacc[g]);
    }
  }

  // staging: all 512 thr, row sm = tid>>5, chunk sc = tid&31
  const int sm = tid >> 5;
  const int sc = tid & 31;
  const f16* spg = hs + (size_t)(bb + sm) * Tsz * 256 + sc * 8;
  const f16* spn = spg + 3 * 256;
  f16x8 ld;
  {
    *(f16x8*)(&xq[1][sm][sc * 8]) = *(const f16x8*)(spg + 256);
    ld = *(const f16x8*)(spg + 2 * 256);
  }

  __syncthreads();

  for (int t = 0; t < Tsz; ++t) {
    // x-frags for t+1 from staging buffer
    f16x8 xa[8];
    if (t + 1 < Tsz) {
      const f16* xrow = &xq[(t + 1) & 1][l15][0];
#pragma unroll
      for (int kt = 0; kt < 8; ++kt) xa[kt] = *(const f16x8*)(xrow + kt * 32 + q * 8);
    }

    f16x8 ah[4];
#pragma unroll
    for (int kt = 0; kt < 4; ++kt)
      ah[kt] = *(const f16x8*)(&hq[t & 1][l15][kt * 32 + q * 8]);
#pragma unroll
    for (int kt = 0; kt < 4; ++kt)
#pragma unroll
      for (int g = 0; g < 4; ++g) gacc[g] = MFMA(ah[kt], wh[g][kt], gacc[g]);

#pragma unroll
    for (int r = 0; r < 4; ++r) {
      const float h = lstm_cell(gacc[0][r], gacc[1][r], gacc[2][r], gacc[3][r], cst[r]);
      hq[(t + 1) & 1][4 * q + r][jcol] = (f16)h;
      if (t == Tsz - 1) hfinal[(size_t)(bb + 4 * q + r) * Hsz + jcol] = h;
    }

    // staging pipeline: publish x(t+2), load x(t+3)
    if (t + 2 < Tsz) *(f16x8*)(&xq[t & 1][sm][sc * 8]) = ld;
    if (t + 3 < Tsz) { ld = *(const f16x8*)spn; spn += 256; }

    // x-projection for t+1: independent chains, off the recurrent path
    if (t + 1 < Tsz) {
      floatx4 nacc[4];
#pragma unroll
      for (int g = 0; g < 4; ++g) {
        nacc[g][0] = bsum[g]; nacc[g][1] = bsum[g];
        nacc[g][2] = bsum[g]; nacc[g][3] = bsum[g];
      }
#pragma unroll
      for (int kt = 0; kt < 8; ++kt)
#pragma unroll
        for (int g = 0; g < 4; ++g) nacc[g] = MFMA(xa[kt], wi[g][kt], nacc[g]);
#pragma unroll
      for (int g = 0; g < 4; ++g) gacc[g] = nacc[g];
    }
    lds_barrier();
  }
}

// L1-reverse single step (h0=c0=0 -> Whh term vanishes) + FC head. 1 block/batch.
__global__ __launch_bounds__(512) void tail_kernel(
    const f16* __restrict__ hs, const float* __restrict__ hfinal,
    const float* __restrict__ Wr, const float* __restrict__ br1,
    const float* __restrict__ br2, const float* __restrict__ fc1w,
    const float* __restrict__ fc1b, const float* __restrict__ fc2w,
    const float* __restrict__ fc2b, float* __restrict__ out) {
  const int b = blockIdx.x;
  const int tid = threadIdx.x;
  __shared__ float hrow[256];
  __shared__ float gact[512];
  __shared__ float last[256];
  __shared__ float hid[128];
  __shared__ float psum[128];

  const size_t row = ((size_t)b * Tsz + (Tsz - 1)) * 256;
  if (tid < 256) hrow[tid] = (float)hs[row + tid];
  __syncthreads();

  {
    float a = br1[tid] + br2[tid];
    const float* wr = Wr + (size_t)tid * 256;
#pragma unroll 8
    for (int k = 0; k < 256; ++k) a += hrow[k] * wr[k];
    gact[tid] = (tid >= 256 && tid < 384) ? tanh_f(a) : sigm_f(a);
  }
  __syncthreads();

  if (tid < 128) {
    const float c = gact[tid] * gact[256 + tid];      // sig(i)*tanh(g), c0=0
    const float hb = gact[384 + tid] * tanh_f(c);
    last[tid] = hfinal[(size_t)b * Hsz + tid];
    last[128 + tid] = hb;
  }
  __syncthreads();

  if (tid < 128) {
    float a = fc1b[tid];
    const float* w1 = fc1w + (size_t)tid * 256;
#pragma unroll 8
    for (int k = 0; k < 256; ++k) a += last[k] * w1[k];
    hid[tid] = fmaxf(a, 0.f);
  }
  __syncthreads();
  if (tid < 128) psum[tid] = hid[tid] * fc2w[tid];
  __syncthreads();
  if (tid == 0) {
    float s = fc2b[0];
    for (int k = 0; k < 128; ++k) s += psum[k];
    out[b] = s;
  }
}

extern "C" void kernel_launch(void* const* d_in, const int* in_sizes, int n_in,
                              void* d_out, int out_size, void* d_ws, size_t ws_size,
                              hipStream_t stream) {
  (void)in_sizes; (void)n_in; (void)out_size;
  const float* x = (const float*)d_in[0];
  const float* Wih_l0 = (const float*)d_in[1];
  const float* Whh_l0 = (const float*)d_in[2];
  const float* bih_l0 = (const float*)d_in[3];
  const float* bhh_l0 = (const float*)d_in[4];
  const float* Wih_l0r = (const float*)d_in[5];
  const float* Whh_l0r = (const float*)d_in[6];
  const float* bih_l0r = (const float*)d_in[7];
  const float* bhh_l0r = (const float*)d_in[8];
  const float* Wih_l1 = (const float*)d_in[9];
  const float* Whh_l1 = (const float*)d_in[10];
  const float* bih_l1 = (const float*)d_in[11];
  const float* bhh_l1 = (const float*)d_in[12];
  const float* Wih_l1r = (const float*)d_in[13];
  // d_in[14] = W_hh_l1r unused (reverse h0 = 0)
  const float* bih_l1r = (const float*)d_in[15];
  const float* bhh_l1r = (const float*)d_in[16];
  const float* fc1w = (const float*)d_in[17];
  const float* fc1b = (const float*)d_in[18];
  const float* fc2w = (const float*)d_in[19];
  const float* fc2b = (const float*)d_in[20];
  float* out = (float*)d_out;

  char* ws = (char*)d_ws;
  const size_t M = (size_t)Bsz * Tsz;        // 131072
  const size_t XFB = M * Isz * 2;            // 16.8 MB  x in f16
  const size_t HSB = M * 256 * 2;            // 67.1 MB  hs in f16
  const size_t HFB = (size_t)Bsz * Hsz * 4;  // 131 KB   L1 fwd final h
  const size_t need = XFB + HSB + HFB;
  if (ws_size < need) return;  // fail clean (absmax), not fault

  size_t off = 0;
  f16* xf = (f16*)(ws + off); off += XFB;
  f16* hsb = (f16*)(ws + off); off += HSB;
  float* hfinal = (float*)(ws + off); off += HFB;

  const int n4 = (int)(M * Isz / 4);
  cvt_f32_f16<<<dim3((n4 + 255) / 256), dim3(256), 0, stream>>>(x, xf, n4);

  lstm_scan_l0<<<dim3(32), dim3(512), 0, stream>>>(
      xf, Wih_l0, Whh_l0, bih_l0, bhh_l0, Wih_l0r, Whh_l0r, bih_l0r, bhh_l0r, hsb);

  lstm_scan_l1<<<dim3(16), dim3(512), 0, stream>>>(
      hsb, Wih_l1, Whh_l1, bih_l1, bhh_l1, hfinal);

  tail_kernel<<<dim3(256), dim3(512), 0, stream>>>(
      hsb, hfinal, Wih_l1r, bih_l1r, bhh_l1r, fc1w, fc1b, fc2w, fc2b, out);
}

// Round 6
// 1179.146 us; speedup vs baseline: 1.7501x; 1.3493x over previous
//
#include <hip/hip_runtime.h>

#define Bsz 256
#define Tsz 512
#define Isz 64
#define Hsz 128
#define G4  512   // 4*H

typedef _Float16 f16;
typedef _Float16 f16x8 __attribute__((ext_vector_type(8)));
typedef _Float16 f16x4 __attribute__((ext_vector_type(4)));
typedef float floatx4 __attribute__((ext_vector_type(4)));

#define MFMA(A, B, C) __builtin_amdgcn_mfma_f32_16x16x32_f16((A), (B), (C), 0, 0, 0)

// LDS-only barrier: drains lgkmcnt but NOT vmcnt -> in-loop global traffic
// (x/xg prefetch loads, hs stores) never serializes a step.
__device__ __forceinline__ void lds_barrier() {
  asm volatile("s_waitcnt lgkmcnt(0)\n\ts_barrier" ::: "memory");
}

__device__ __forceinline__ float sigm_f(float x) {
  float e = __builtin_amdgcn_exp2f(x * -1.4426950408889634f);
  return __builtin_amdgcn_rcpf(1.0f + e);
}
__device__ __forceinline__ float tanh_f(float x) {
  float e = __builtin_amdgcn_exp2f(x * -2.8853900817779268f);
  return 2.0f * __builtin_amdgcn_rcpf(1.0f + e) - 1.0f;
}

__global__ void cvt_f32_f16(const float* __restrict__ in, f16* __restrict__ out, int n4) {
  int i = blockIdx.x * blockDim.x + threadIdx.x;
  if (i < n4) {
    float4 v = ((const float4*)in)[i];
    f16x4 o;
    o[0] = (f16)v.x; o[1] = (f16)v.y; o[2] = (f16)v.z; o[3] = (f16)v.w;
    ((f16x4*)out)[i] = o;
  }
}

__device__ __forceinline__ f16x8 load_wfrag(const float* __restrict__ W, int n, int stride, int k) {
  const float* p = W + (size_t)n * stride + k;
  float4 a = *(const float4*)p;
  float4 b = *(const float4*)(p + 4);
  f16x8 r;
  r[0] = (f16)a.x; r[1] = (f16)a.y; r[2] = (f16)a.z; r[3] = (f16)a.w;
  r[4] = (f16)b.x; r[5] = (f16)b.y; r[6] = (f16)b.z; r[7] = (f16)b.w;
  return r;
}

// Shared-denominator LSTM cell: 5 exp2 + 2 rcp.
__device__ __forceinline__ float lstm_cell(float ipre, float fpre, float gpre,
                                           float opre, float& c) {
  const float ei = __builtin_amdgcn_exp2f(fminf(ipre * -1.4426950408889634f, 30.f));
  const float ef = __builtin_amdgcn_exp2f(fminf(fpre * -1.4426950408889634f, 30.f));
  const float eg = __builtin_amdgcn_exp2f(fminf(gpre * -2.8853900817779268f, 30.f));
  const float eo = __builtin_amdgcn_exp2f(fminf(opre * -1.4426950408889634f, 30.f));
  const float pf1 = 1.f + ef;
  const float P = (1.f + ei) * (1.f + eg);
  const float num = fmaf(c, P, pf1 * (1.f - eg));
  const float cn = num * __builtin_amdgcn_rcpf(pf1 * P);
  c = cn;
  const float ec = __builtin_amdgcn_exp2f(fminf(cn * -2.8853900817779268f, 30.f));
  return (1.f - ec) * __builtin_amdgcn_rcpf((1.f + eo) * (1.f + ec));
}

// Layer-0 BiLSTM scan. 32 blocks x 512 thr (16 batches each; 0..15 fwd,
// 16..31 rev). Wave w owns j-slice [16w,16w+16) of all 4 gates. x-frags are
// per-lane GLOBAL loads (2 KB/step unique, L1 serves the 8x wave duplication;
// keeps the LDS pipe for h). x-proj MFMAs run off the recurrent path.
__global__ __launch_bounds__(512, 1) void lstm_scan_l0(
    const f16* __restrict__ xf,
    const float* __restrict__ Wih_f, const float* __restrict__ Whh_f,
    const float* __restrict__ bih_f, const float* __restrict__ bhh_f,
    const float* __restrict__ Wih_r, const float* __restrict__ Whh_r,
    const float* __restrict__ bih_r, const float* __restrict__ bhh_r,
    f16* __restrict__ hs) {
  const int dir = ((int)blockIdx.x >= 16) ? 1 : 0;
  const int bb = ((int)blockIdx.x & 15) * 16;
  const float* __restrict__ Wih = dir ? Wih_r : Wih_f;
  const float* __restrict__ Whh = dir ? Whh_r : Whh_f;
  const float* __restrict__ bih = dir ? bih_r : bih_f;
  const float* __restrict__ bhh = dir ? bhh_r : bhh_f;

  __shared__ __align__(16) f16 hq[2][16][136];

  const int tid = threadIdx.x;
  const int lane = tid & 63;
  const int w = tid >> 6;
  const int l15 = lane & 15;
  const int q = lane >> 4;
  const int jcol = w * 16 + l15;

  f16x8 wi[4][2], wh[4][4];
  float bsum[4];
#pragma unroll
  for (int g = 0; g < 4; ++g) {
    const int n = g * 128 + jcol;
#pragma unroll
    for (int kt = 0; kt < 2; ++kt) wi[g][kt] = load_wfrag(Wih, n, Isz, kt * 32 + q * 8);
#pragma unroll
    for (int kt = 0; kt < 4; ++kt) wh[g][kt] = load_wfrag(Whh, n, Hsz, kt * 32 + q * 8);
    bsum[g] = bih[n] + bhh[n];
  }

  for (int i = tid; i < 2 * 16 * 136; i += 512) (&hq[0][0][0])[i] = (f16)0.f;

  float cst[4] = {0.f, 0.f, 0.f, 0.f};
  const int t0 = dir ? (Tsz - 1) : 0;
  const int dt = dir ? -1 : 1;
  const ptrdiff_t xstep = (ptrdiff_t)dt * Isz;

  // per-lane x pointer: row bb+l15, k = q*8 (+32 for second frag)
  const f16* xp = xf + ((size_t)(bb + l15) * Tsz + t0) * Isz + q * 8;

  // prime gacc = bias + xproj(t0); prefetch x(t0+dt)
  floatx4 gacc[4];
  {
    f16x8 x0 = *(const f16x8*)xp;
    f16x8 x1 = *(const f16x8*)(xp + 32);
    xp += xstep;
#pragma unroll
    for (int g = 0; g < 4; ++g) {
      gacc[g][0] = bsum[g]; gacc[g][1] = bsum[g];
      gacc[g][2] = bsum[g]; gacc[g][3] = bsum[g];
      gacc[g] = MFMA(x0, wi[g][0], gacc[g]);
      gacc[g] = MFMA(x1, wi[g][1], gacc[g]);
    }
  }
  f16x8 xb0 = *(const f16x8*)xp;
  f16x8 xb1 = *(const f16x8*)(xp + 32);
  xp += xstep;

  f16* hsp = hs + ((size_t)(bb + 4 * q) * Tsz + t0) * 256 + dir * 128 + jcol;
  const ptrdiff_t hstep = (ptrdiff_t)dt * 256;

  __syncthreads();

  for (int t = 0; t < Tsz; ++t) {
    f16x8 ah[4];
#pragma unroll
    for (int kt = 0; kt < 4; ++kt)
      ah[kt] = *(const f16x8*)(&hq[t & 1][l15][kt * 32 + q * 8]);
#pragma unroll
    for (int kt = 0; kt < 4; ++kt)
#pragma unroll
      for (int g = 0; g < 4; ++g) gacc[g] = MFMA(ah[kt], wh[g][kt], gacc[g]);

#pragma unroll
    for (int r = 0; r < 4; ++r) {
      const float h = lstm_cell(gacc[0][r], gacc[1][r], gacc[2][r], gacc[3][r], cst[r]);
      const f16 hf = (f16)h;
      hq[(t + 1) & 1][4 * q + r][jcol] = hf;
      hsp[(size_t)r * Tsz * 256] = hf;
    }
    hsp += hstep;

    // x-projection for t+1 from frags loaded last step; then prefetch x(t+2)
    if (t + 1 < Tsz) {
#pragma unroll
      for (int g = 0; g < 4; ++g) {
        floatx4 na;
        na[0] = bsum[g]; na[1] = bsum[g]; na[2] = bsum[g]; na[3] = bsum[g];
        na = MFMA(xb0, wi[g][0], na);
        na = MFMA(xb1, wi[g][1], na);
        gacc[g] = na;
      }
      if (t + 2 < Tsz) {
        xb0 = *(const f16x8*)xp;
        xb1 = *(const f16x8*)(xp + 32);
        xp += xstep;
      }
    }
    lds_barrier();
  }
}

// xg GEMM for layer-1 fwd: xg[sb][t][w][slot<32][16] f16 = per-lane fragment
// layout (4 gates x 4 rows contiguous), biases folded in. Grid 256 = 32 sb x
// 8 t-chunks; block = 8 batches x 64 ts x 512 gates.
__global__ __launch_bounds__(512, 1) void xg_gemm_l1(
    const f16* __restrict__ hs, const float* __restrict__ Wih,
    const float* __restrict__ bih, const float* __restrict__ bhh,
    f16* __restrict__ xg) {
  const int sb = (int)blockIdx.x & 31;
  const int tc = (int)blockIdx.x >> 5;

  const int tid = threadIdx.x;
  const int lane = tid & 63;
  const int w = tid >> 6;
  const int l15 = lane & 15;
  const int q = lane >> 4;
  const int jcol = w * 16 + l15;

  f16x8 wi[4][8];
  float bsum[4];
#pragma unroll
  for (int g = 0; g < 4; ++g) {
    const int n = g * 128 + jcol;
#pragma unroll
    for (int kt = 0; kt < 8; ++kt) wi[g][kt] = load_wfrag(Wih, n, 256, kt * 32 + q * 8);
    bsum[g] = bih[n] + bhh[n];
  }

  const int row = sb * 8 + (l15 & 7);  // rows 8..15 duplicate 0..7 (never stored)
  const f16* ap = hs + ((size_t)row * Tsz + tc * 64) * 256 + q * 8;
  f16* op = xg + ((((size_t)sb * Tsz + tc * 64) * 8 + w) * 32 + q * 16 + l15) * 16;

  for (int tt = 0; tt < 64; ++tt) {
    f16x8 a[8];
#pragma unroll
    for (int kt = 0; kt < 8; ++kt) a[kt] = *(const f16x8*)(ap + kt * 32);
    ap += 256;

    floatx4 acc[4];
#pragma unroll
    for (int g = 0; g < 4; ++g) {
      acc[g][0] = bsum[g]; acc[g][1] = bsum[g];
      acc[g][2] = bsum[g]; acc[g][3] = bsum[g];
    }
#pragma unroll
    for (int kt = 0; kt < 8; ++kt)
#pragma unroll
      for (int g = 0; g < 4; ++g) acc[g] = MFMA(a[kt], wi[g][kt], acc[g]);

    if (q < 2) {
      f16x8 o0, o1;
#pragma unroll
      for (int e = 0; e < 8; ++e) {
        o0[e] = (f16)acc[e >> 2][e & 3];
        o1[e] = (f16)acc[2 + (e >> 2)][e & 3];
      }
      *(f16x8*)op = o0;
      *(f16x8*)(op + 8) = o1;
    }
    op += 4096;
  }
}

// Layer-1 forward scan from precomputed xg. 32 blocks x 8 batches (rows 8..15
// of the MFMA tile are exact duplicates of 0..7 -> no garbage, no masks except
// the hfinal store). Per step: 32B/lane coalesced xg load (3-deep prefetch),
// ah LDS reads, 16 recurrent MFMA, in-register cell. LDS-only barrier.
__global__ __launch_bounds__(512, 1) void lstm_scan_l1x(
    const f16* __restrict__ xg, const float* __restrict__ Whh,
    float* __restrict__ hfinal) {
  const int sb = (int)blockIdx.x;

  __shared__ __align__(16) f16 hq[2][16][136];

  const int tid = threadIdx.x;
  const int lane = tid & 63;
  const int w = tid >> 6;
  const int l15 = lane & 15;
  const int q = lane >> 4;
  const int jcol = w * 16 + l15;

  f16x8 wh[4][4];
#pragma unroll
  for (int g = 0; g < 4; ++g) {
    const int n = g * 128 + jcol;
#pragma unroll
    for (int kt = 0; kt < 4; ++kt) wh[g][kt] = load_wfrag(Whh, n, Hsz, kt * 32 + q * 8);
  }

  for (int i = tid; i < 2 * 16 * 136; i += 512) (&hq[0][0][0])[i] = (f16)0.f;

  float cst[4] = {0.f, 0.f, 0.f, 0.f};

  // lanes q>=2 read the q&1 slot (duplicate data, keeps everything finite)
  const int slot = (q & 1) * 16 + l15;
  const f16* gp = xg + ((size_t)sb * Tsz * 8 + w) * 512 + slot * 16;
  // 3-deep prefetch: b0=xg(0), b1=xg(1), b2=xg(2)
  f16x8 b0a = *(const f16x8*)gp,          b0b = *(const f16x8*)(gp + 8);
  f16x8 b1a = *(const f16x8*)(gp + 4096), b1b = *(const f16x8*)(gp + 4104);
  f16x8 b2a = *(const f16x8*)(gp + 8192), b2b = *(const f16x8*)(gp + 8200);
  gp += 3 * 4096;

  __syncthreads();

  for (int t = 0; t < Tsz; ++t) {
    f16x8 ah[4];
#pragma unroll
    for (int kt = 0; kt < 4; ++kt)
      ah[kt] = *(const f16x8*)(&hq[t & 1][l15][kt * 32 + q * 8]);

    floatx4 gacc[4];
#pragma unroll
    for (int g = 0; g < 4; ++g)
#pragma unroll
      for (int r = 0; r < 4; ++r) {
        const int e = g * 4 + r;
        gacc[g][r] = (e < 8) ? (float)b0a[e] : (float)b0b[e - 8];
      }
#pragma unroll
    for (int kt = 0; kt < 4; ++kt)
#pragma unroll
      for (int g = 0; g < 4; ++g) gacc[g] = MFMA(ah[kt], wh[g][kt], gacc[g]);

#pragma unroll
    for (int r = 0; r < 4; ++r) {
      const float h = lstm_cell(gacc[0][r], gacc[1][r], gacc[2][r], gacc[3][r], cst[r]);
      hq[(t + 1) & 1][4 * q + r][jcol] = (f16)h;
      if (t == Tsz - 1 && q < 2)
        hfinal[(size_t)(sb * 8 + 4 * q + r) * Hsz + jcol] = h;
    }

    // rotate prefetch ring, load xg(t+3)
    b0a = b1a; b0b = b1b;
    b1a = b2a; b1b = b2b;
    if (t + 3 < Tsz) {
      b2a = *(const f16x8*)gp;
      b2b = *(const f16x8*)(gp + 8);
      gp += 4096;
    }
    lds_barrier();
  }
}

// Fallback layer-1 scan (round-5 style, reads hs directly) for small ws.
__global__ __launch_bounds__(512, 1) void lstm_scan_l1_fb(
    const f16* __restrict__ hs,
    const float* __restrict__ Wih, const float* __restrict__ Whh,
    const float* __restrict__ bih, const float* __restrict__ bhh,
    float* __restrict__ hfinal) {
  const int bb = (int)blockIdx.x * 16;
  __shared__ __align__(16) f16 hq[2][16][136];
  __shared__ __align__(16) f16 xq[2][16][264];

  const int tid = threadIdx.x;
  const int lane = tid & 63;
  const int w = tid >> 6;
  const int l15 = lane & 15;
  const int q = lane >> 4;
  const int jcol = w * 16 + l15;

  f16x8 wi[4][8], wh[4][4];
  float bsum[4];
#pragma unroll
  for (int g = 0; g < 4; ++g) {
    const int n = g * 128 + jcol;
#pragma unroll
    for (int kt = 0; kt < 8; ++kt) wi[g][kt] = load_wfrag(Wih, n, 256, kt * 32 + q * 8);
#pragma unroll
    for (int kt = 0; kt < 4; ++kt) wh[g][kt] = load_wfrag(Whh, n, Hsz, kt * 32 + q * 8);
    bsum[g] = bih[n] + bhh[n];
  }
  for (int i = tid; i < 2 * 16 * 136; i += 512) (&hq[0][0][0])[i] = (f16)0.f;
  float cst[4] = {0.f, 0.f, 0.f, 0.f};

  floatx4 gacc[4];
  {
    const f16* pp = hs + (size_t)(bb + l15) * Tsz * 256 + q * 8;
#pragma unroll
    for (int g = 0; g < 4; ++g) {
      gacc[g][0] = bsum[g]; gacc[g][1] = bsum[g];
      gacc[g][2] = bsum[g]; gacc[g][3] = bsum[g];
    }
#pragma unroll
    for (int kt = 0; kt < 8; ++kt) {
      f16x8 xa = *(const f16x8*)(pp + kt * 32);
#pragma unroll
      for (int g = 0; g < 4; ++g) gacc[g] = MFMA(xa, wi[g][kt], gacc[g]);
    }
  }
  const int sm = tid >> 5;
  const int sc = tid & 31;
  const f16* spg = hs + (size_t)(bb + sm) * Tsz * 256 + sc * 8;
  const f16* spn = spg + 3 * 256;
  f16x8 ld;
  *(f16x8*)(&xq[1][sm][sc * 8]) = *(const f16x8*)(spg + 256);
  ld = *(const f16x8*)(spg + 2 * 256);
  __syncthreads();

  for (int t = 0; t < Tsz; ++t) {
    f16x8 xa[8];
    if (t + 1 < Tsz) {
      const f16* xrow = &xq[(t + 1) & 1][l15][0];
#pragma unroll
      for (int kt = 0; kt < 8; ++kt) xa[kt] = *(const f16x8*)(xrow + kt * 32 + q * 8);
    }
    f16x8 ah[4];
#pragma unroll
    for (int kt = 0; kt < 4; ++kt)
      ah[kt] = *(const f16x8*)(&hq[t & 1][l15][kt * 32 + q * 8]);
#pragma unroll
    for (int kt = 0; kt < 4; ++kt)
#pragma unroll
      for (int g = 0; g < 4; ++g) gacc[g] = MFMA(ah[kt], wh[g][kt], gacc[g]);

#pragma unroll
    for (int r = 0; r < 4; ++r) {
      const float h = lstm_cell(gacc[0][r], gacc[1][r], gacc[2][r], gacc[3][r], cst[r]);
      hq[(t + 1) & 1][4 * q + r][jcol] = (f16)h;
      if (t == Tsz - 1) hfinal[(size_t)(bb + 4 * q + r) * Hsz + jcol] = h;
    }
    if (t + 2 < Tsz) *(f16x8*)(&xq[t & 1][sm][sc * 8]) = ld;
    if (t + 3 < Tsz) { ld = *(const f16x8*)spn; spn += 256; }
    if (t + 1 < Tsz) {
      floatx4 nacc[4];
#pragma unroll
      for (int g = 0; g < 4; ++g) {
        nacc[g][0] = bsum[g]; nacc[g][1] = bsum[g];
        nacc[g][2] = bsum[g]; nacc[g][3] = bsum[g];
      }
#pragma unroll
      for (int kt = 0; kt < 8; ++kt)
#pragma unroll
        for (int g = 0; g < 4; ++g) nacc[g] = MFMA(xa[kt], wi[g][kt], nacc[g]);
#pragma unroll
      for (int g = 0; g < 4; ++g) gacc[g] = nacc[g];
    }
    lds_barrier();
  }
}

// L1-reverse single step (h0=c0=0) + FC head. 1 block/batch.
__global__ __launch_bounds__(512) void tail_kernel(
    const f16* __restrict__ hs, const float* __restrict__ hfinal,
    const float* __restrict__ Wr, const float* __restrict__ br1,
    const float* __restrict__ br2, const float* __restrict__ fc1w,
    const float* __restrict__ fc1b, const float* __restrict__ fc2w,
    const float* __restrict__ fc2b, float* __restrict__ out) {
  const int b = blockIdx.x;
  const int tid = threadIdx.x;
  __shared__ float hrow[256];
  __shared__ float gact[512];
  __shared__ float last[256];
  __shared__ float hid[128];
  __shared__ float psum[128];

  const size_t row = ((size_t)b * Tsz + (Tsz - 1)) * 256;
  if (tid < 256) hrow[tid] = (float)hs[row + tid];
  __syncthreads();

  {
    float a = br1[tid] + br2[tid];
    const float* wr = Wr + (size_t)tid * 256;
#pragma unroll 8
    for (int k = 0; k < 256; ++k) a += hrow[k] * wr[k];
    gact[tid] = (tid >= 256 && tid < 384) ? tanh_f(a) : sigm_f(a);
  }
  __syncthreads();

  if (tid < 128) {
    const float c = gact[tid] * gact[256 + tid];
    const float hb = gact[384 + tid] * tanh_f(c);
    last[tid] = hfinal[(size_t)b * Hsz + tid];
    last[128 + tid] = hb;
  }
  __syncthreads();

  if (tid < 128) {
    float a = fc1b[tid];
    const float* w1 = fc1w + (size_t)tid * 256;
#pragma unroll 8
    for (int k = 0; k < 256; ++k) a += last[k] * w1[k];
    hid[tid] = fmaxf(a, 0.f);
  }
  __syncthreads();
  if (tid < 128) psum[tid] = hid[tid] * fc2w[tid];
  __syncthreads();
  if (tid == 0) {
    float s = fc2b[0];
    for (int k = 0; k < 128; ++k) s += psum[k];
    out[b] = s;
  }
}

extern "C" void kernel_launch(void* const* d_in, const int* in_sizes, int n_in,
                              void* d_out, int out_size, void* d_ws, size_t ws_size,
                              hipStream_t stream) {
  (void)in_sizes; (void)n_in; (void)out_size;
  const float* x = (const float*)d_in[0];
  const float* Wih_l0 = (const float*)d_in[1];
  const float* Whh_l0 = (const float*)d_in[2];
  const float* bih_l0 = (const float*)d_in[3];
  const float* bhh_l0 = (const float*)d_in[4];
  const float* Wih_l0r = (const float*)d_in[5];
  const float* Whh_l0r = (const float*)d_in[6];
  const float* bih_l0r = (const float*)d_in[7];
  const float* bhh_l0r = (const float*)d_in[8];
  const float* Wih_l1 = (const float*)d_in[9];
  const float* Whh_l1 = (const float*)d_in[10];
  const float* bih_l1 = (const float*)d_in[11];
  const float* bhh_l1 = (const float*)d_in[12];
  const float* Wih_l1r = (const float*)d_in[13];
  // d_in[14] = W_hh_l1r unused (reverse h0 = 0)
  const float* bih_l1r = (const float*)d_in[15];
  const float* bhh_l1r = (const float*)d_in[16];
  const float* fc1w = (const float*)d_in[17];
  const float* fc1b = (const float*)d_in[18];
  const float* fc2w = (const float*)d_in[19];
  const float* fc2b = (const float*)d_in[20];
  float* out = (float*)d_out;

  char* ws = (char*)d_ws;
  const size_t M = (size_t)Bsz * Tsz;        // 131072
  const size_t XFB = M * Isz * 2;            // 16.8 MB  x in f16
  const size_t HSB = M * 256 * 2;            // 67.1 MB  hs in f16
  const size_t HFB = (size_t)Bsz * Hsz * 4;  // 131 KB   L1 fwd final h
  const size_t XGB = (size_t)32 * Tsz * 8 * 32 * 16 * 2;  // 134 MB l1 xg f16
  const size_t need_min = XFB + HSB + HFB;
  const size_t need_full = need_min + XGB;
  if (ws_size < need_min) return;
  const bool fast = ws_size >= need_full;

  size_t off = 0;
  f16* xf = (f16*)(ws + off); off += XFB;
  f16* hsb = (f16*)(ws + off); off += HSB;
  float* hfinal = (float*)(ws + off); off += HFB;
  f16* xgb = fast ? (f16*)(ws + off) : nullptr;

  const int n4 = (int)(M * Isz / 4);
  cvt_f32_f16<<<dim3((n4 + 255) / 256), dim3(256), 0, stream>>>(x, xf, n4);

  lstm_scan_l0<<<dim3(32), dim3(512), 0, stream>>>(
      xf, Wih_l0, Whh_l0, bih_l0, bhh_l0, Wih_l0r, Whh_l0r, bih_l0r, bhh_l0r, hsb);

  if (fast) {
    xg_gemm_l1<<<dim3(256), dim3(512), 0, stream>>>(hsb, Wih_l1, bih_l1, bhh_l1, xgb);
    lstm_scan_l1x<<<dim3(32), dim3(512), 0, stream>>>(xgb, Whh_l1, hfinal);
  } else {
    lstm_scan_l1_fb<<<dim3(16), dim3(512), 0, stream>>>(
        hsb, Wih_l1, Whh_l1, bih_l1, bhh_l1, hfinal);
  }

  tail_kernel<<<dim3(256), dim3(512), 0, stream>>>(
      hsb, hfinal, Wih_l1r, bih_l1r, bhh_l1r, fc1w, fc1b, fc2w, fc2b, out);
}

// Round 7
// 871.736 us; speedup vs baseline: 2.3672x; 1.3526x over previous
//
#include <hip/hip_runtime.h>

#define Bsz 256
#define Tsz 512
#define Isz 64
#define Hsz 128
#define G4  512   // 4*H

typedef _Float16 f16;
typedef _Float16 f16x8 __attribute__((ext_vector_type(8)));
typedef _Float16 f16x4 __attribute__((ext_vector_type(4)));
typedef float floatx4 __attribute__((ext_vector_type(4)));

#define MFMA(A, B, C) __builtin_amdgcn_mfma_f32_16x16x32_f16((A), (B), (C), 0, 0, 0)

// LDS-only barrier: drains lgkmcnt but NOT vmcnt -> in-loop global traffic
// (prefetch loads, hs stores) never serializes a step.
__device__ __forceinline__ void lds_barrier() {
  asm volatile("s_waitcnt lgkmcnt(0)\n\ts_barrier" ::: "memory");
}

__device__ __forceinline__ float sigm_f(float x) {
  float e = __builtin_amdgcn_exp2f(x * -1.4426950408889634f);
  return __builtin_amdgcn_rcpf(1.0f + e);
}
__device__ __forceinline__ float tanh_f(float x) {
  float e = __builtin_amdgcn_exp2f(x * -2.8853900817779268f);
  return 2.0f * __builtin_amdgcn_rcpf(1.0f + e) - 1.0f;
}

__global__ void cvt_f32_f16(const float* __restrict__ in, f16* __restrict__ out, int n4) {
  int i = blockIdx.x * blockDim.x + threadIdx.x;
  if (i < n4) {
    float4 v = ((const float4*)in)[i];
    f16x4 o;
    o[0] = (f16)v.x; o[1] = (f16)v.y; o[2] = (f16)v.z; o[3] = (f16)v.w;
    ((f16x4*)out)[i] = o;
  }
}

__device__ __forceinline__ f16x8 load_wfrag(const float* __restrict__ W, int n, int stride, int k) {
  const float* p = W + (size_t)n * stride + k;
  float4 a = *(const float4*)p;
  float4 b = *(const float4*)(p + 4);
  f16x8 r;
  r[0] = (f16)a.x; r[1] = (f16)a.y; r[2] = (f16)a.z; r[3] = (f16)a.w;
  r[4] = (f16)b.x; r[5] = (f16)b.y; r[6] = (f16)b.z; r[7] = (f16)b.w;
  return r;
}

// Shared-denominator LSTM cell: 5 exp2 + 2 rcp.
__device__ __forceinline__ float lstm_cell(float ipre, float fpre, float gpre,
                                           float opre, float& c) {
  const float ei = __builtin_amdgcn_exp2f(fminf(ipre * -1.4426950408889634f, 30.f));
  const float ef = __builtin_amdgcn_exp2f(fminf(fpre * -1.4426950408889634f, 30.f));
  const float eg = __builtin_amdgcn_exp2f(fminf(gpre * -2.8853900817779268f, 30.f));
  const float eo = __builtin_amdgcn_exp2f(fminf(opre * -1.4426950408889634f, 30.f));
  const float pf1 = 1.f + ef;
  const float P = (1.f + ei) * (1.f + eg);
  const float num = fmaf(c, P, pf1 * (1.f - eg));
  const float cn = num * __builtin_amdgcn_rcpf(pf1 * P);
  c = cn;
  const float ec = __builtin_amdgcn_exp2f(fminf(cn * -2.8853900817779268f, 30.f));
  return (1.f - ec) * __builtin_amdgcn_rcpf((1.f + eo) * (1.f + ec));
}

// Extract acc[r=q] (row 4q+q == lane's batch) with 3 cndmask.
__device__ __forceinline__ float sel_q(const floatx4& a, bool qb0, bool qb1) {
  const float a01 = qb0 ? a[1] : a[0];
  const float a23 = qb0 ? a[3] : a[2];
  return qb1 ? a23 : a01;
}

// Layer-0 BiLSTM scan, 4 batches/block (rows duplicated mod 4 in the MFMA
// tile; only reg r=q consumed -> 1 cell/lane). 128 blocks (0..63 fwd,
// 64..127 rev) x 512 thr. Wave w owns j-slice [16w,16w+16) of all 4 gates.
// x-proj MFMAs off the recurrent path; LDS-only barrier; hq hot set ~1 KB.
__global__ __launch_bounds__(512, 1) void lstm_scan_l0(
    const f16* __restrict__ xf,
    const float* __restrict__ Wih_f, const float* __restrict__ Whh_f,
    const float* __restrict__ bih_f, const float* __restrict__ bhh_f,
    const float* __restrict__ Wih_r, const float* __restrict__ Whh_r,
    const float* __restrict__ bih_r, const float* __restrict__ bhh_r,
    f16* __restrict__ hs) {
  const int dir = ((int)blockIdx.x >= 64) ? 1 : 0;
  const int bb = ((int)blockIdx.x & 63) * 4;
  const float* __restrict__ Wih = dir ? Wih_r : Wih_f;
  const float* __restrict__ Whh = dir ? Whh_r : Whh_f;
  const float* __restrict__ bih = dir ? bih_r : bih_f;
  const float* __restrict__ bhh = dir ? bhh_r : bhh_f;

  __shared__ __align__(16) f16 hq[2][4][136];

  const int tid = threadIdx.x;
  const int lane = tid & 63;
  const int w = tid >> 6;
  const int l15 = lane & 15;
  const int q = lane >> 4;
  const int jcol = w * 16 + l15;
  const int mrow = l15 & 3;            // A-tile row -> batch (bb + mrow)
  const bool qb0 = (q & 1) != 0;
  const bool qb1 = (q & 2) != 0;

  f16x8 wi[4][2], wh[4][4];
  float bsum[4];
#pragma unroll
  for (int g = 0; g < 4; ++g) {
    const int n = g * 128 + jcol;
#pragma unroll
    for (int kt = 0; kt < 2; ++kt) wi[g][kt] = load_wfrag(Wih, n, Isz, kt * 32 + q * 8);
#pragma unroll
    for (int kt = 0; kt < 4; ++kt) wh[g][kt] = load_wfrag(Whh, n, Hsz, kt * 32 + q * 8);
    bsum[g] = bih[n] + bhh[n];
  }

  for (int i = tid; i < 2 * 4 * 136; i += 512) (&hq[0][0][0])[i] = (f16)0.f;

  float cst = 0.f;                     // c-state: 1 cell/lane (batch q, j jcol)
  const int t0 = dir ? (Tsz - 1) : 0;
  const int dt = dir ? -1 : 1;
  const ptrdiff_t xstep = (ptrdiff_t)dt * Isz;

  const f16* xp = xf + ((size_t)(bb + mrow) * Tsz + t0) * Isz + q * 8;

  floatx4 gacc[4];
  {
    f16x8 x0 = *(const f16x8*)xp;
    f16x8 x1 = *(const f16x8*)(xp + 32);
    xp += xstep;
#pragma unroll
    for (int g = 0; g < 4; ++g) {
      gacc[g][0] = bsum[g]; gacc[g][1] = bsum[g];
      gacc[g][2] = bsum[g]; gacc[g][3] = bsum[g];
      gacc[g] = MFMA(x0, wi[g][0], gacc[g]);
      gacc[g] = MFMA(x1, wi[g][1], gacc[g]);
    }
  }
  f16x8 xb0 = *(const f16x8*)xp;
  f16x8 xb1 = *(const f16x8*)(xp + 32);
  xp += xstep;

  // per-lane hs store: batch bb+q, col dir*128+jcol
  f16* hsp = hs + ((size_t)(bb + q) * Tsz + t0) * 256 + dir * 128 + jcol;
  const ptrdiff_t hstep = (ptrdiff_t)dt * 256;

  __syncthreads();

  for (int t = 0; t < Tsz; ++t) {
    f16x8 ah[4];
#pragma unroll
    for (int kt = 0; kt < 4; ++kt)
      ah[kt] = *(const f16x8*)(&hq[t & 1][mrow][kt * 32 + q * 8]);
#pragma unroll
    for (int kt = 0; kt < 4; ++kt)
#pragma unroll
      for (int g = 0; g < 4; ++g) gacc[g] = MFMA(ah[kt], wh[g][kt], gacc[g]);

    const float h = lstm_cell(sel_q(gacc[0], qb0, qb1), sel_q(gacc[1], qb0, qb1),
                              sel_q(gacc[2], qb0, qb1), sel_q(gacc[3], qb0, qb1), cst);
    const f16 hf = (f16)h;
    hq[(t + 1) & 1][q][jcol] = hf;
    *hsp = hf;
    hsp += hstep;

    if (t + 1 < Tsz) {
#pragma unroll
      for (int g = 0; g < 4; ++g) {
        floatx4 na;
        na[0] = bsum[g]; na[1] = bsum[g]; na[2] = bsum[g]; na[3] = bsum[g];
        na = MFMA(xb0, wi[g][0], na);
        na = MFMA(xb1, wi[g][1], na);
        gacc[g] = na;
      }
      if (t + 2 < Tsz) {
        xb0 = *(const f16x8*)xp;
        xb1 = *(const f16x8*)(xp + 32);
        xp += xstep;
      }
    }
    lds_barrier();
  }
}

// xg GEMM for layer-1 fwd. Output layout: xg[sb][t][w][l15][r*4+g] f16
// (sb = 4-batch scan block, biases folded) so each scan lane reads ONE
// coalesced f16x4. Grid 256 = 16 batch-groups x 16 t-chunks of 32.
__global__ __launch_bounds__(512, 1) void xg_gemm_l1(
    const f16* __restrict__ hs, const float* __restrict__ Wih,
    const float* __restrict__ bih, const float* __restrict__ bhh,
    f16* __restrict__ xg) {
  const int bg = (int)blockIdx.x & 15;
  const int tc = (int)blockIdx.x >> 4;
  const int bb = bg * 16;

  const int tid = threadIdx.x;
  const int lane = tid & 63;
  const int w = tid >> 6;
  const int l15 = lane & 15;
  const int q = lane >> 4;
  const int jcol = w * 16 + l15;

  f16x8 wi[4][8];
  float bsum[4];
#pragma unroll
  for (int g = 0; g < 4; ++g) {
    const int n = g * 128 + jcol;
#pragma unroll
    for (int kt = 0; kt < 8; ++kt) wi[g][kt] = load_wfrag(Wih, n, 256, kt * 32 + q * 8);
    bsum[g] = bih[n] + bhh[n];
  }

  const f16* ap = hs + ((size_t)(bb + l15) * Tsz + tc * 32) * 256 + q * 8;
  // lane owns sb = bg*4 + q (its quad's 4 batches, r = batch-in-block)
  f16* op = xg + ((((size_t)(bg * 4 + q) * Tsz + tc * 32) * 8 + w) * 16 + l15) * 16;

  for (int tt = 0; tt < 32; ++tt) {
    f16x8 a[8];
#pragma unroll
    for (int kt = 0; kt < 8; ++kt) a[kt] = *(const f16x8*)(ap + kt * 32);
    ap += 256;

    floatx4 acc[4];
#pragma unroll
    for (int g = 0; g < 4; ++g) {
      acc[g][0] = bsum[g]; acc[g][1] = bsum[g];
      acc[g][2] = bsum[g]; acc[g][3] = bsum[g];
    }
#pragma unroll
    for (int kt = 0; kt < 8; ++kt)
#pragma unroll
      for (int g = 0; g < 4; ++g) acc[g] = MFMA(a[kt], wi[g][kt], acc[g]);

    f16x8 o0, o1;
#pragma unroll
    for (int e = 0; e < 8; ++e) {
      o0[e] = (f16)acc[e & 3][e >> 2];       // e = r*4+g, r=e>>2, g=e&3
      o1[e] = (f16)acc[e & 3][2 + (e >> 2)];
    }
    *(f16x8*)op = o0;
    *(f16x8*)(op + 8) = o1;
    op += 2048;                               // next t
  }
}

// Layer-1 forward scan from precomputed xg. 64 blocks x 4 batches; 1 cell/
// lane; 8 B coalesced xg load, 3-deep prefetch; LDS-only barrier.
__global__ __launch_bounds__(512, 1) void lstm_scan_l1x(
    const f16* __restrict__ xg, const float* __restrict__ Whh,
    float* __restrict__ hfinal) {
  const int sb = (int)blockIdx.x;

  __shared__ __align__(16) f16 hq[2][4][136];

  const int tid = threadIdx.x;
  const int lane = tid & 63;
  const int w = tid >> 6;
  const int l15 = lane & 15;
  const int q = lane >> 4;
  const int jcol = w * 16 + l15;
  const int mrow = l15 & 3;
  const bool qb0 = (q & 1) != 0;
  const bool qb1 = (q & 2) != 0;

  f16x8 wh[4][4];
#pragma unroll
  for (int g = 0; g < 4; ++g) {
    const int n = g * 128 + jcol;
#pragma unroll
    for (int kt = 0; kt < 4; ++kt) wh[g][kt] = load_wfrag(Whh, n, Hsz, kt * 32 + q * 8);
  }

  for (int i = tid; i < 2 * 4 * 136; i += 512) (&hq[0][0][0])[i] = (f16)0.f;

  float cst = 0.f;

  const f16* gp = xg + (((size_t)sb * Tsz * 8 + w) * 16 + l15) * 16 + q * 4;
  f16x4 b0 = *(const f16x4*)gp;
  f16x4 b1 = *(const f16x4*)(gp + 2048);
  f16x4 b2 = *(const f16x4*)(gp + 4096);
  gp += 3 * 2048;

  __syncthreads();

  for (int t = 0; t < Tsz; ++t) {
    f16x8 ah[4];
#pragma unroll
    for (int kt = 0; kt < 4; ++kt)
      ah[kt] = *(const f16x8*)(&hq[t & 1][mrow][kt * 32 + q * 8]);

    floatx4 gacc[4];
#pragma unroll
    for (int g = 0; g < 4; ++g) {
      const float v = (float)b0[g];            // broadcast: only r=q consumed
      gacc[g][0] = v; gacc[g][1] = v; gacc[g][2] = v; gacc[g][3] = v;
    }
#pragma unroll
    for (int kt = 0; kt < 4; ++kt)
#pragma unroll
      for (int g = 0; g < 4; ++g) gacc[g] = MFMA(ah[kt], wh[g][kt], gacc[g]);

    const float h = lstm_cell(sel_q(gacc[0], qb0, qb1), sel_q(gacc[1], qb0, qb1),
                              sel_q(gacc[2], qb0, qb1), sel_q(gacc[3], qb0, qb1), cst);
    hq[(t + 1) & 1][q][jcol] = (f16)h;
    if (t == Tsz - 1)
      hfinal[(size_t)(sb * 4 + q) * Hsz + jcol] = h;

    b0 = b1; b1 = b2;
    if (t + 3 < Tsz) {
      b2 = *(const f16x4*)gp;
      gp += 2048;
    }
    lds_barrier();
  }
}

// Fallback layer-1 scan (reads hs directly) for small ws. 16 blocks.
__global__ __launch_bounds__(512, 1) void lstm_scan_l1_fb(
    const f16* __restrict__ hs,
    const float* __restrict__ Wih, const float* __restrict__ Whh,
    const float* __restrict__ bih, const float* __restrict__ bhh,
    float* __restrict__ hfinal) {
  const int bb = (int)blockIdx.x * 16;
  __shared__ __align__(16) f16 hq[2][16][136];
  __shared__ __align__(16) f16 xq[2][16][264];

  const int tid = threadIdx.x;
  const int lane = tid & 63;
  const int w = tid >> 6;
  const int l15 = lane & 15;
  const int q = lane >> 4;
  const int jcol = w * 16 + l15;

  f16x8 wi[4][8], wh[4][4];
  float bsum[4];
#pragma unroll
  for (int g = 0; g < 4; ++g) {
    const int n = g * 128 + jcol;
#pragma unroll
    for (int kt = 0; kt < 8; ++kt) wi[g][kt] = load_wfrag(Wih, n, 256, kt * 32 + q * 8);
#pragma unroll
    for (int kt = 0; kt < 4; ++kt) wh[g][kt] = load_wfrag(Whh, n, Hsz, kt * 32 + q * 8);
    bsum[g] = bih[n] + bhh[n];
  }
  for (int i = tid; i < 2 * 16 * 136; i += 512) (&hq[0][0][0])[i] = (f16)0.f;
  float cst[4] = {0.f, 0.f, 0.f, 0.f};

  floatx4 gacc[4];
  {
    const f16* pp = hs + (size_t)(bb + l15) * Tsz * 256 + q * 8;
#pragma unroll
    for (int g = 0; g < 4; ++g) {
      gacc[g][0] = bsum[g]; gacc[g][1] = bsum[g];
      gacc[g][2] = bsum[g]; gacc[g][3] = bsum[g];
    }
#pragma unroll
    for (int kt = 0; kt < 8; ++kt) {
      f16x8 xa = *(const f16x8*)(pp + kt * 32);
#pragma unroll
      for (int g = 0; g < 4; ++g) gacc[g] = MFMA(xa, wi[g][kt], gacc[g]);
    }
  }
  const int sm = tid >> 5;
  const int sc = tid & 31;
  const f16* spg = hs + (size_t)(bb + sm) * Tsz * 256 + sc * 8;
  const f16* spn = spg + 3 * 256;
  f16x8 ld;
  *(f16x8*)(&xq[1][sm][sc * 8]) = *(const f16x8*)(spg + 256);
  ld = *(const f16x8*)(spg + 2 * 256);
  __syncthreads();

  for (int t = 0; t < Tsz; ++t) {
    f16x8 xa[8];
    if (t + 1 < Tsz) {
      const f16* xrow = &xq[(t + 1) & 1][l15][0];
#pragma unroll
      for (int kt = 0; kt < 8; ++kt) xa[kt] = *(const f16x8*)(xrow + kt * 32 + q * 8);
    }
    f16x8 ah[4];
#pragma unroll
    for (int kt = 0; kt < 4; ++kt)
      ah[kt] = *(const f16x8*)(&hq[t & 1][l15][kt * 32 + q * 8]);
#pragma unroll
    for (int kt = 0; kt < 4; ++kt)
#pragma unroll
      for (int g = 0; g < 4; ++g) gacc[g] = MFMA(ah[kt], wh[g][kt], gacc[g]);

#pragma unroll
    for (int r = 0; r < 4; ++r) {
      const float h = lstm_cell(gacc[0][r], gacc[1][r], gacc[2][r], gacc[3][r], cst[r]);
      hq[(t + 1) & 1][4 * q + r][jcol] = (f16)h;
      if (t == Tsz - 1) hfinal[(size_t)(bb + 4 * q + r) * Hsz + jcol] = h;
    }
    if (t + 2 < Tsz) *(f16x8*)(&xq[t & 1][sm][sc * 8]) = ld;
    if (t + 3 < Tsz) { ld = *(const f16x8*)spn; spn += 256; }
    if (t + 1 < Tsz) {
      floatx4 nacc[4];
#pragma unroll
      for (int g = 0; g < 4; ++g) {
        nacc[g][0] = bsum[g]; nacc[g][1] = bsum[g];
        nacc[g][2] = bsum[g]; nacc[g][3] = bsum[g];
      }
#pragma unroll
      for (int kt = 0; kt < 8; ++kt)
#pragma unroll
        for (int g = 0; g < 4; ++g) nacc[g] = MFMA(xa[kt], wi[g][kt], nacc[g]);
#pragma unroll
      for (int g = 0; g < 4; ++g) gacc[g] = nacc[g];
    }
    lds_barrier();
  }
}

// L1-reverse single step (h0=c0=0) + FC head. 1 block/batch.
__global__ __launch_bounds__(512) void tail_kernel(
    const f16* __restrict__ hs, const float* __restrict__ hfinal,
    const float* __restrict__ Wr, const float* __restrict__ br1,
    const float* __restrict__ br2, const float* __restrict__ fc1w,
    const float* __restrict__ fc1b, const float* __restrict__ fc2w,
    const float* __restrict__ fc2b, float* __restrict__ out) {
  const int b = blockIdx.x;
  const int tid = threadIdx.x;
  __shared__ float hrow[256];
  __shared__ float gact[512];
  __shared__ float last[256];
  __shared__ float hid[128];
  __shared__ float psum[128];

  const size_t row = ((size_t)b * Tsz + (Tsz - 1)) * 256;
  if (tid < 256) hrow[tid] = (float)hs[row + tid];
  __syncthreads();

  {
    float a = br1[tid] + br2[tid];
    const float* wr = Wr + (size_t)tid * 256;
#pragma unroll 8
    for (int k = 0; k < 256; ++k) a += hrow[k] * wr[k];
    gact[tid] = (tid >= 256 && tid < 384) ? tanh_f(a) : sigm_f(a);
  }
  __syncthreads();

  if (tid < 128) {
    const float c = gact[tid] * gact[256 + tid];
    const float hb = gact[384 + tid] * tanh_f(c);
    last[tid] = hfinal[(size_t)b * Hsz + tid];
    last[128 + tid] = hb;
  }
  __syncthreads();

  if (tid < 128) {
    float a = fc1b[tid];
    const float* w1 = fc1w + (size_t)tid * 256;
#pragma unroll 8
    for (int k = 0; k < 256; ++k) a += last[k] * w1[k];
    hid[tid] = fmaxf(a, 0.f);
  }
  __syncthreads();
  if (tid < 128) psum[tid] = hid[tid] * fc2w[tid];
  __syncthreads();
  if (tid == 0) {
    float s = fc2b[0];
    for (int k = 0; k < 128; ++k) s += psum[k];
    out[b] = s;
  }
}

extern "C" void kernel_launch(void* const* d_in, const int* in_sizes, int n_in,
                              void* d_out, int out_size, void* d_ws, size_t ws_size,
                              hipStream_t stream) {
  (void)in_sizes; (void)n_in; (void)out_size;
  const float* x = (const float*)d_in[0];
  const float* Wih_l0 = (const float*)d_in[1];
  const float* Whh_l0 = (const float*)d_in[2];
  const float* bih_l0 = (const float*)d_in[3];
  const float* bhh_l0 = (const float*)d_in[4];
  const float* Wih_l0r = (const float*)d_in[5];
  const float* Whh_l0r = (const float*)d_in[6];
  const float* bih_l0r = (const float*)d_in[7];
  const float* bhh_l0r = (const float*)d_in[8];
  const float* Wih_l1 = (const float*)d_in[9];
  const float* Whh_l1 = (const float*)d_in[10];
  const float* bih_l1 = (const float*)d_in[11];
  const float* bhh_l1 = (const float*)d_in[12];
  const float* Wih_l1r = (const float*)d_in[13];
  // d_in[14] = W_hh_l1r unused (reverse h0 = 0)
  const float* bih_l1r = (const float*)d_in[15];
  const float* bhh_l1r = (const float*)d_in[16];
  const float* fc1w = (const float*)d_in[17];
  const float* fc1b = (const float*)d_in[18];
  const float* fc2w = (const float*)d_in[19];
  const float* fc2b = (const float*)d_in[20];
  float* out = (float*)d_out;

  char* ws = (char*)d_ws;
  const size_t M = (size_t)Bsz * Tsz;        // 131072
  const size_t XFB = M * Isz * 2;            // 16.8 MB  x in f16
  const size_t HSB = M * 256 * 2;            // 67.1 MB  hs in f16
  const size_t HFB = (size_t)Bsz * Hsz * 4;  // 131 KB   L1 fwd final h
  const size_t XGB = (size_t)64 * Tsz * 8 * 16 * 16 * 2;  // 134 MB l1 xg f16
  const size_t need_min = XFB + HSB + HFB;
  const size_t need_full = need_min + XGB;
  if (ws_size < need_min) return;
  const bool fast = ws_size >= need_full;

  size_t off = 0;
  f16* xf = (f16*)(ws + off); off += XFB;
  f16* hsb = (f16*)(ws + off); off += HSB;
  float* hfinal = (float*)(ws + off); off += HFB;
  f16* xgb = fast ? (f16*)(ws + off) : nullptr;

  const int n4 = (int)(M * Isz / 4);
  cvt_f32_f16<<<dim3((n4 + 255) / 256), dim3(256), 0, stream>>>(x, xf, n4);

  lstm_scan_l0<<<dim3(128), dim3(512), 0, stream>>>(
      xf, Wih_l0, Whh_l0, bih_l0, bhh_l0, Wih_l0r, Whh_l0r, bih_l0r, bhh_l0r, hsb);

  if (fast) {
    xg_gemm_l1<<<dim3(256), dim3(512), 0, stream>>>(hsb, Wih_l1, bih_l1, bhh_l1, xgb);
    lstm_scan_l1x<<<dim3(64), dim3(512), 0, stream>>>(xgb, Whh_l1, hfinal);
  } else {
    lstm_scan_l1_fb<<<dim3(16), dim3(512), 0, stream>>>(
        hsb, Wih_l1, Whh_l1, bih_l1, bhh_l1, hfinal);
  }

  tail_kernel<<<dim3(256), dim3(512), 0, stream>>>(
      hsb, hfinal, Wih_l1r, bih_l1r, bhh_l1r, fc1w, fc1b, fc2w, fc2b, out);
}

// Round 8
// 770.498 us; speedup vs baseline: 2.6783x; 1.1314x over previous
//
#include <hip/hip_runtime.h>

#define Bsz 256
#define Tsz 512
#define Isz 64
#define Hsz 128
#define G4  512   // 4*H

typedef _Float16 f16;
typedef _Float16 f16x8 __attribute__((ext_vector_type(8)));
typedef _Float16 f16x4 __attribute__((ext_vector_type(4)));
typedef float floatx4 __attribute__((ext_vector_type(4)));

#define MFMA(A, B, C) __builtin_amdgcn_mfma_f32_16x16x32_f16((A), (B), (C), 0, 0, 0)

// LDS-only barrier: drains lgkmcnt but NOT vmcnt -> in-loop global traffic
// (prefetch loads, hs stores) never serializes a step.
__device__ __forceinline__ void lds_barrier() {
  asm volatile("s_waitcnt lgkmcnt(0)\n\ts_barrier" ::: "memory");
}

__device__ __forceinline__ float sigm_f(float x) {
  float e = __builtin_amdgcn_exp2f(x * -1.4426950408889634f);
  return __builtin_amdgcn_rcpf(1.0f + e);
}
__device__ __forceinline__ float tanh_f(float x) {
  float e = __builtin_amdgcn_exp2f(x * -2.8853900817779268f);
  return 2.0f * __builtin_amdgcn_rcpf(1.0f + e) - 1.0f;
}

__global__ void cvt_f32_f16(const float* __restrict__ in, f16* __restrict__ out, int n4) {
  int i = blockIdx.x * blockDim.x + threadIdx.x;
  if (i < n4) {
    float4 v = ((const float4*)in)[i];
    f16x4 o;
    o[0] = (f16)v.x; o[1] = (f16)v.y; o[2] = (f16)v.z; o[3] = (f16)v.w;
    ((f16x4*)out)[i] = o;
  }
}

__device__ __forceinline__ f16x8 load_wfrag(const float* __restrict__ W, int n, int stride, int k) {
  const float* p = W + (size_t)n * stride + k;
  float4 a = *(const float4*)p;
  float4 b = *(const float4*)(p + 4);
  f16x8 r;
  r[0] = (f16)a.x; r[1] = (f16)a.y; r[2] = (f16)a.z; r[3] = (f16)a.w;
  r[4] = (f16)b.x; r[5] = (f16)b.y; r[6] = (f16)b.z; r[7] = (f16)b.w;
  return r;
}

// Shared-denominator LSTM cell: 5 exp2 + 2 rcp.
__device__ __forceinline__ float lstm_cell(float ipre, float fpre, float gpre,
                                           float opre, float& c) {
  const float ei = __builtin_amdgcn_exp2f(fminf(ipre * -1.4426950408889634f, 30.f));
  const float ef = __builtin_amdgcn_exp2f(fminf(fpre * -1.4426950408889634f, 30.f));
  const float eg = __builtin_amdgcn_exp2f(fminf(gpre * -2.8853900817779268f, 30.f));
  const float eo = __builtin_amdgcn_exp2f(fminf(opre * -1.4426950408889634f, 30.f));
  const float pf1 = 1.f + ef;
  const float P = (1.f + ei) * (1.f + eg);
  const float num = fmaf(c, P, pf1 * (1.f - eg));
  const float cn = num * __builtin_amdgcn_rcpf(pf1 * P);
  c = cn;
  const float ec = __builtin_amdgcn_exp2f(fminf(cn * -2.8853900817779268f, 30.f));
  return (1.f - ec) * __builtin_amdgcn_rcpf((1.f + eo) * (1.f + ec));
}

// Extract acc[r=q] (row 4q+q == lane's batch) with 3 cndmask.
__device__ __forceinline__ float sel_q(const floatx4& a, bool qb0, bool qb1) {
  const float a01 = qb0 ? a[1] : a[0];
  const float a23 = qb0 ? a[3] : a[2];
  return qb1 ? a23 : a01;
}

// Layer-0 BiLSTM scan, 4 batches/block, 1 cell/lane. 128 blocks (0..63 fwd,
// 64..127 rev) x 512 thr. Depth-4 x-prefetch ring, NO register copies (t-loop
// unrolled x4, each body owns a fixed slot) -> load->use distance = 4 steps,
// no per-step vmcnt drain. hq stride 144: 2-way-max LDS aliasing (free).
__global__ __launch_bounds__(512, 1) void lstm_scan_l0(
    const f16* __restrict__ xf,
    const float* __restrict__ Wih_f, const float* __restrict__ Whh_f,
    const float* __restrict__ bih_f, const float* __restrict__ bhh_f,
    const float* __restrict__ Wih_r, const float* __restrict__ Whh_r,
    const float* __restrict__ bih_r, const float* __restrict__ bhh_r,
    f16* __restrict__ hs) {
  const int dir = ((int)blockIdx.x >= 64) ? 1 : 0;
  const int bb = ((int)blockIdx.x & 63) * 4;
  const float* __restrict__ Wih = dir ? Wih_r : Wih_f;
  const float* __restrict__ Whh = dir ? Whh_r : Whh_f;
  const float* __restrict__ bih = dir ? bih_r : bih_f;
  const float* __restrict__ bhh = dir ? bhh_r : bhh_f;

  __shared__ __align__(16) f16 hq[2][4][144];

  const int tid = threadIdx.x;
  const int lane = tid & 63;
  const int w = tid >> 6;
  const int l15 = lane & 15;
  const int q = lane >> 4;
  const int jcol = w * 16 + l15;
  const int mrow = l15 & 3;
  const bool qb0 = (q & 1) != 0;
  const bool qb1 = (q & 2) != 0;

  f16x8 wi[4][2], wh[4][4];
  float bsum[4];
#pragma unroll
  for (int g = 0; g < 4; ++g) {
    const int n = g * 128 + jcol;
#pragma unroll
    for (int kt = 0; kt < 2; ++kt) wi[g][kt] = load_wfrag(Wih, n, Isz, kt * 32 + q * 8);
#pragma unroll
    for (int kt = 0; kt < 4; ++kt) wh[g][kt] = load_wfrag(Whh, n, Hsz, kt * 32 + q * 8);
    bsum[g] = bih[n] + bhh[n];
  }

  for (int i = tid; i < 2 * 4 * 144; i += 512) (&hq[0][0][0])[i] = (f16)0.f;

  float cst = 0.f;
  const int t0 = dir ? (Tsz - 1) : 0;
  const int dt = dir ? -1 : 1;
  const ptrdiff_t xstep = (ptrdiff_t)dt * Isz;

  const f16* xp = xf + ((size_t)(bb + mrow) * Tsz + t0) * Isz + q * 8;

  // prime gacc = bias + xproj(t0)
  floatx4 gacc[4];
  {
    f16x8 x0 = *(const f16x8*)xp;
    f16x8 x1 = *(const f16x8*)(xp + 32);
#pragma unroll
    for (int g = 0; g < 4; ++g) {
      gacc[g][0] = bsum[g]; gacc[g][1] = bsum[g];
      gacc[g][2] = bsum[g]; gacc[g][3] = bsum[g];
      gacc[g] = MFMA(x0, wi[g][0], gacc[g]);
      gacc[g] = MFMA(x1, wi[g][1], gacc[g]);
    }
  }

  // ring slot s holds x(t+1) for steps t == s (mod 4); primed with x(1..4)
  f16x8 r0a = *(const f16x8*)(xp + 1 * xstep), r0b = *(const f16x8*)(xp + 1 * xstep + 32);
  f16x8 r1a = *(const f16x8*)(xp + 2 * xstep), r1b = *(const f16x8*)(xp + 2 * xstep + 32);
  f16x8 r2a = *(const f16x8*)(xp + 3 * xstep), r2b = *(const f16x8*)(xp + 3 * xstep + 32);
  f16x8 r3a = *(const f16x8*)(xp + 4 * xstep), r3b = *(const f16x8*)(xp + 4 * xstep + 32);
  const f16* xpn = xp + 5 * xstep;   // next address to load: x(t+5) at step t

  f16* hsp = hs + ((size_t)(bb + q) * Tsz + t0) * 256 + dir * 128 + jcol;
  const ptrdiff_t hstep = (ptrdiff_t)dt * 256;

  __syncthreads();

  auto step = [&](int t, f16x8& ra, f16x8& rb) {
    f16x8 ah[4];
#pragma unroll
    for (int kt = 0; kt < 4; ++kt)
      ah[kt] = *(const f16x8*)(&hq[t & 1][mrow][kt * 32 + q * 8]);
#pragma unroll
    for (int kt = 0; kt < 4; ++kt)
#pragma unroll
      for (int g = 0; g < 4; ++g) gacc[g] = MFMA(ah[kt], wh[g][kt], gacc[g]);

    const float h = lstm_cell(sel_q(gacc[0], qb0, qb1), sel_q(gacc[1], qb0, qb1),
                              sel_q(gacc[2], qb0, qb1), sel_q(gacc[3], qb0, qb1), cst);
    const f16 hf = (f16)h;
    hq[(t + 1) & 1][q][jcol] = hf;
    *hsp = hf;
    hsp += hstep;

    if (t + 1 < Tsz) {
      // xproj for t+1 from this body's ring slot (loaded 4 steps ago)
#pragma unroll
      for (int g = 0; g < 4; ++g) {
        floatx4 na;
        na[0] = bsum[g]; na[1] = bsum[g]; na[2] = bsum[g]; na[3] = bsum[g];
        na = MFMA(ra, wi[g][0], na);
        na = MFMA(rb, wi[g][1], na);
        gacc[g] = na;
      }
      // refill this slot with x(t+5), consumed at step t+4
      if (t + 5 < Tsz) {
        ra = *(const f16x8*)xpn;
        rb = *(const f16x8*)(xpn + 32);
        xpn += xstep;
      }
    }
    lds_barrier();
  };

  for (int tb = 0; tb < Tsz; tb += 4) {
    step(tb + 0, r0a, r0b);
    step(tb + 1, r1a, r1b);
    step(tb + 2, r2a, r2b);
    step(tb + 3, r3a, r3b);
  }
}

// xg GEMM for layer-1 fwd. Output layout: xg[sb][t][w][l15][r*4+g] f16
// (sb = 4-batch scan block, biases folded) so each scan lane reads ONE
// coalesced f16x4. Grid 256 = 16 batch-groups x 16 t-chunks of 32.
__global__ __launch_bounds__(512, 1) void xg_gemm_l1(
    const f16* __restrict__ hs, const float* __restrict__ Wih,
    const float* __restrict__ bih, const float* __restrict__ bhh,
    f16* __restrict__ xg) {
  const int bg = (int)blockIdx.x & 15;
  const int tc = (int)blockIdx.x >> 4;
  const int bb = bg * 16;

  const int tid = threadIdx.x;
  const int lane = tid & 63;
  const int w = tid >> 6;
  const int l15 = lane & 15;
  const int q = lane >> 4;
  const int jcol = w * 16 + l15;

  f16x8 wi[4][8];
  float bsum[4];
#pragma unroll
  for (int g = 0; g < 4; ++g) {
    const int n = g * 128 + jcol;
#pragma unroll
    for (int kt = 0; kt < 8; ++kt) wi[g][kt] = load_wfrag(Wih, n, 256, kt * 32 + q * 8);
    bsum[g] = bih[n] + bhh[n];
  }

  const f16* ap = hs + ((size_t)(bb + l15) * Tsz + tc * 32) * 256 + q * 8;
  f16* op = xg + ((((size_t)(bg * 4 + q) * Tsz + tc * 32) * 8 + w) * 16 + l15) * 16;

  for (int tt = 0; tt < 32; ++tt) {
    f16x8 a[8];
#pragma unroll
    for (int kt = 0; kt < 8; ++kt) a[kt] = *(const f16x8*)(ap + kt * 32);
    ap += 256;

    floatx4 acc[4];
#pragma unroll
    for (int g = 0; g < 4; ++g) {
      acc[g][0] = bsum[g]; acc[g][1] = bsum[g];
      acc[g][2] = bsum[g]; acc[g][3] = bsum[g];
    }
#pragma unroll
    for (int kt = 0; kt < 8; ++kt)
#pragma unroll
      for (int g = 0; g < 4; ++g) acc[g] = MFMA(a[kt], wi[g][kt], acc[g]);

    f16x8 o0, o1;
#pragma unroll
    for (int e = 0; e < 8; ++e) {
      o0[e] = (f16)acc[e & 3][e >> 2];       // e = r*4+g
      o1[e] = (f16)acc[e & 3][2 + (e >> 2)];
    }
    *(f16x8*)op = o0;
    *(f16x8*)(op + 8) = o1;
    op += 2048;
  }
}

// Layer-1 forward scan from precomputed xg. 64 blocks x 4 batches, 1 cell/
// lane. Depth-4 prefetch ring, no copies (unrolled x4). LDS-only barrier.
__global__ __launch_bounds__(512, 1) void lstm_scan_l1x(
    const f16* __restrict__ xg, const float* __restrict__ Whh,
    float* __restrict__ hfinal) {
  const int sb = (int)blockIdx.x;

  __shared__ __align__(16) f16 hq[2][4][144];

  const int tid = threadIdx.x;
  const int lane = tid & 63;
  const int w = tid >> 6;
  const int l15 = lane & 15;
  const int q = lane >> 4;
  const int jcol = w * 16 + l15;
  const int mrow = l15 & 3;
  const bool qb0 = (q & 1) != 0;
  const bool qb1 = (q & 2) != 0;

  f16x8 wh[4][4];
#pragma unroll
  for (int g = 0; g < 4; ++g) {
    const int n = g * 128 + jcol;
#pragma unroll
    for (int kt = 0; kt < 4; ++kt) wh[g][kt] = load_wfrag(Whh, n, Hsz, kt * 32 + q * 8);
  }

  for (int i = tid; i < 2 * 4 * 144; i += 512) (&hq[0][0][0])[i] = (f16)0.f;

  float cst = 0.f;

  const f16* gp = xg + (((size_t)sb * Tsz * 8 + w) * 16 + l15) * 16 + q * 4;
  // ring slot s = xg(t) for t == s (mod 4); primed with xg(0..3)
  f16x4 s0 = *(const f16x4*)gp;
  f16x4 s1 = *(const f16x4*)(gp + 2048);
  f16x4 s2 = *(const f16x4*)(gp + 4096);
  f16x4 s3 = *(const f16x4*)(gp + 6144);
  const f16* gpn = gp + 4 * 2048;   // next load: xg(t+4) at step t

  __syncthreads();

  auto step = [&](int t, f16x4& sl) {
    f16x8 ah[4];
#pragma unroll
    for (int kt = 0; kt < 4; ++kt)
      ah[kt] = *(const f16x8*)(&hq[t & 1][mrow][kt * 32 + q * 8]);

    floatx4 gacc[4];
#pragma unroll
    for (int g = 0; g < 4; ++g) {
      const float v = (float)sl[g];
      gacc[g][0] = v; gacc[g][1] = v; gacc[g][2] = v; gacc[g][3] = v;
    }
#pragma unroll
    for (int kt = 0; kt < 4; ++kt)
#pragma unroll
      for (int g = 0; g < 4; ++g) gacc[g] = MFMA(ah[kt], wh[g][kt], gacc[g]);

    const float h = lstm_cell(sel_q(gacc[0], qb0, qb1), sel_q(gacc[1], qb0, qb1),
                              sel_q(gacc[2], qb0, qb1), sel_q(gacc[3], qb0, qb1), cst);
    hq[(t + 1) & 1][q][jcol] = (f16)h;
    if (t == Tsz - 1)
      hfinal[(size_t)(sb * 4 + q) * Hsz + jcol] = h;

    // refill this slot with xg(t+4)
    if (t + 4 < Tsz) {
      sl = *(const f16x4*)gpn;
      gpn += 2048;
    }
    lds_barrier();
  };

  for (int tb = 0; tb < Tsz; tb += 4) {
    step(tb + 0, s0);
    step(tb + 1, s1);
    step(tb + 2, s2);
    step(tb + 3, s3);
  }
}

// Fallback layer-1 scan (reads hs directly) for small ws. 16 blocks.
__global__ __launch_bounds__(512, 1) void lstm_scan_l1_fb(
    const f16* __restrict__ hs,
    const float* __restrict__ Wih, const float* __restrict__ Whh,
    const float* __restrict__ bih, const float* __restrict__ bhh,
    float* __restrict__ hfinal) {
  const int bb = (int)blockIdx.x * 16;
  __shared__ __align__(16) f16 hq[2][16][136];
  __shared__ __align__(16) f16 xq[2][16][264];

  const int tid = threadIdx.x;
  const int lane = tid & 63;
  const int w = tid >> 6;
  const int l15 = lane & 15;
  const int q = lane >> 4;
  const int jcol = w * 16 + l15;

  f16x8 wi[4][8], wh[4][4];
  float bsum[4];
#pragma unroll
  for (int g = 0; g < 4; ++g) {
    const int n = g * 128 + jcol;
#pragma unroll
    for (int kt = 0; kt < 8; ++kt) wi[g][kt] = load_wfrag(Wih, n, 256, kt * 32 + q * 8);
#pragma unroll
    for (int kt = 0; kt < 4; ++kt) wh[g][kt] = load_wfrag(Whh, n, Hsz, kt * 32 + q * 8);
    bsum[g] = bih[n] + bhh[n];
  }
  for (int i = tid; i < 2 * 16 * 136; i += 512) (&hq[0][0][0])[i] = (f16)0.f;
  float cst[4] = {0.f, 0.f, 0.f, 0.f};

  floatx4 gacc[4];
  {
    const f16* pp = hs + (size_t)(bb + l15) * Tsz * 256 + q * 8;
#pragma unroll
    for (int g = 0; g < 4; ++g) {
      gacc[g][0] = bsum[g]; gacc[g][1] = bsum[g];
      gacc[g][2] = bsum[g]; gacc[g][3] = bsum[g];
    }
#pragma unroll
    for (int kt = 0; kt < 8; ++kt) {
      f16x8 xa = *(const f16x8*)(pp + kt * 32);
#pragma unroll
      for (int g = 0; g < 4; ++g) gacc[g] = MFMA(xa, wi[g][kt], gacc[g]);
    }
  }
  const int sm = tid >> 5;
  const int sc = tid & 31;
  const f16* spg = hs + (size_t)(bb + sm) * Tsz * 256 + sc * 8;
  const f16* spn = spg + 3 * 256;
  f16x8 ld;
  *(f16x8*)(&xq[1][sm][sc * 8]) = *(const f16x8*)(spg + 256);
  ld = *(const f16x8*)(spg + 2 * 256);
  __syncthreads();

  for (int t = 0; t < Tsz; ++t) {
    f16x8 xa[8];
    if (t + 1 < Tsz) {
      const f16* xrow = &xq[(t + 1) & 1][l15][0];
#pragma unroll
      for (int kt = 0; kt < 8; ++kt) xa[kt] = *(const f16x8*)(xrow + kt * 32 + q * 8);
    }
    f16x8 ah[4];
#pragma unroll
    for (int kt = 0; kt < 4; ++kt)
      ah[kt] = *(const f16x8*)(&hq[t & 1][l15][kt * 32 + q * 8]);
#pragma unroll
    for (int kt = 0; kt < 4; ++kt)
#pragma unroll
      for (int g = 0; g < 4; ++g) gacc[g] = MFMA(ah[kt], wh[g][kt], gacc[g]);

#pragma unroll
    for (int r = 0; r < 4; ++r) {
      const float h = lstm_cell(gacc[0][r], gacc[1][r], gacc[2][r], gacc[3][r], cst[r]);
      hq[(t + 1) & 1][4 * q + r][jcol] = (f16)h;
      if (t == Tsz - 1) hfinal[(size_t)(bb + 4 * q + r) * Hsz + jcol] = h;
    }
    if (t + 2 < Tsz) *(f16x8*)(&xq[t & 1][sm][sc * 8]) = ld;
    if (t + 3 < Tsz) { ld = *(const f16x8*)spn; spn += 256; }
    if (t + 1 < Tsz) {
      floatx4 nacc[4];
#pragma unroll
      for (int g = 0; g < 4; ++g) {
        nacc[g][0] = bsum[g]; nacc[g][1] = bsum[g];
        nacc[g][2] = bsum[g]; nacc[g][3] = bsum[g];
      }
#pragma unroll
      for (int kt = 0; kt < 8; ++kt)
#pragma unroll
        for (int g = 0; g < 4; ++g) nacc[g] = MFMA(xa[kt], wi[g][kt], nacc[g]);
#pragma unroll
      for (int g = 0; g < 4; ++g) gacc[g] = nacc[g];
    }
    lds_barrier();
  }
}

// L1-reverse single step (h0=c0=0) + FC head. 1 block/batch.
__global__ __launch_bounds__(512) void tail_kernel(
    const f16* __restrict__ hs, const float* __restrict__ hfinal,
    const float* __restrict__ Wr, const float* __restrict__ br1,
    const float* __restrict__ br2, const float* __restrict__ fc1w,
    const float* __restrict__ fc1b, const float* __restrict__ fc2w,
    const float* __restrict__ fc2b, float* __restrict__ out) {
  const int b = blockIdx.x;
  const int tid = threadIdx.x;
  __shared__ float hrow[256];
  __shared__ float gact[512];
  __shared__ float last[256];
  __shared__ float hid[128];
  __shared__ float psum[128];

  const size_t row = ((size_t)b * Tsz + (Tsz - 1)) * 256;
  if (tid < 256) hrow[tid] = (float)hs[row + tid];
  __syncthreads();

  {
    float a = br1[tid] + br2[tid];
    const float* wr = Wr + (size_t)tid * 256;
#pragma unroll 8
    for (int k = 0; k < 256; ++k) a += hrow[k] * wr[k];
    gact[tid] = (tid >= 256 && tid < 384) ? tanh_f(a) : sigm_f(a);
  }
  __syncthreads();

  if (tid < 128) {
    const float c = gact[tid] * gact[256 + tid];
    const float hb = gact[384 + tid] * tanh_f(c);
    last[tid] = hfinal[(size_t)b * Hsz + tid];
    last[128 + tid] = hb;
  }
  __syncthreads();

  if (tid < 128) {
    float a = fc1b[tid];
    const float* w1 = fc1w + (size_t)tid * 256;
#pragma unroll 8
    for (int k = 0; k < 256; ++k) a += last[k] * w1[k];
    hid[tid] = fmaxf(a, 0.f);
  }
  __syncthreads();
  if (tid < 128) psum[tid] = hid[tid] * fc2w[tid];
  __syncthreads();
  if (tid == 0) {
    float s = fc2b[0];
    for (int k = 0; k < 128; ++k) s += psum[k];
    out[b] = s;
  }
}

extern "C" void kernel_launch(void* const* d_in, const int* in_sizes, int n_in,
                              void* d_out, int out_size, void* d_ws, size_t ws_size,
                              hipStream_t stream) {
  (void)in_sizes; (void)n_in; (void)out_size;
  const float* x = (const float*)d_in[0];
  const float* Wih_l0 = (const float*)d_in[1];
  const float* Whh_l0 = (const float*)d_in[2];
  const float* bih_l0 = (const float*)d_in[3];
  const float* bhh_l0 = (const float*)d_in[4];
  const float* Wih_l0r = (const float*)d_in[5];
  const float* Whh_l0r = (const float*)d_in[6];
  const float* bih_l0r = (const float*)d_in[7];
  const float* bhh_l0r = (const float*)d_in[8];
  const float* Wih_l1 = (const float*)d_in[9];
  const float* Whh_l1 = (const float*)d_in[10];
  const float* bih_l1 = (const float*)d_in[11];
  const float* bhh_l1 = (const float*)d_in[12];
  const float* Wih_l1r = (const float*)d_in[13];
  // d_in[14] = W_hh_l1r unused (reverse h0 = 0)
  const float* bih_l1r = (const float*)d_in[15];
  const float* bhh_l1r = (const float*)d_in[16];
  const float* fc1w = (const float*)d_in[17];
  const float* fc1b = (const float*)d_in[18];
  const float* fc2w = (const float*)d_in[19];
  const float* fc2b = (const float*)d_in[20];
  float* out = (float*)d_out;

  char* ws = (char*)d_ws;
  const size_t M = (size_t)Bsz * Tsz;        // 131072
  const size_t XFB = M * Isz * 2;            // 16.8 MB  x in f16
  const size_t HSB = M * 256 * 2;            // 67.1 MB  hs in f16
  const size_t HFB = (size_t)Bsz * Hsz * 4;  // 131 KB   L1 fwd final h
  const size_t XGB = (size_t)64 * Tsz * 8 * 16 * 16 * 2;  // 134 MB l1 xg f16
  const size_t need_min = XFB + HSB + HFB;
  const size_t need_full = need_min + XGB;
  if (ws_size < need_min) return;
  const bool fast = ws_size >= need_full;

  size_t off = 0;
  f16* xf = (f16*)(ws + off); off += XFB;
  f16* hsb = (f16*)(ws + off); off += HSB;
  float* hfinal = (float*)(ws + off); off += HFB;
  f16* xgb = fast ? (f16*)(ws + off) : nullptr;

  const int n4 = (int)(M * Isz / 4);
  cvt_f32_f16<<<dim3((n4 + 255) / 256), dim3(256), 0, stream>>>(x, xf, n4);

  lstm_scan_l0<<<dim3(128), dim3(512), 0, stream>>>(
      xf, Wih_l0, Whh_l0, bih_l0, bhh_l0, Wih_l0r, Whh_l0r, bih_l0r, bhh_l0r, hsb);

  if (fast) {
    xg_gemm_l1<<<dim3(256), dim3(512), 0, stream>>>(hsb, Wih_l1, bih_l1, bhh_l1, xgb);
    lstm_scan_l1x<<<dim3(64), dim3(512), 0, stream>>>(xgb, Whh_l1, hfinal);
  } else {
    lstm_scan_l1_fb<<<dim3(16), dim3(512), 0, stream>>>(
        hsb, Wih_l1, Whh_l1, bih_l1, bhh_l1, hfinal);
  }

  tail_kernel<<<dim3(256), dim3(512), 0, stream>>>(
      hsb, hfinal, Wih_l1r, bih_l1r, bhh_l1r, fc1w, fc1b, fc2w, fc2b, out);
}